// Round 11
// baseline (477.035 us; speedup 1.0000x reference)
//
#include <hip/hip_runtime.h>
#include <hip/hip_bf16.h>
#include <math.h>

#define N 4096
#define IN_FT 512
#define OUT_FT 512
#define COS_THR 0.5f
#define COS_K 10
#define EPSN 1e-12f
#define CAP 256          // max stored nnz per row/col (actual ~10)
#define NW (N / 32)      // bitmask words per row
#define CAP_C 32         // candidate slots per row (10 selected + extras)
#define GAPWIN 2e-4f     // ambiguity window; bf16x3 error bound ~1.5e-5

typedef short s16x8 __attribute__((ext_vector_type(8)));
typedef float f32x4 __attribute__((ext_vector_type(4)));

__device__ __forceinline__ unsigned short f2bf(float f) {
    unsigned u = __float_as_uint(f);
    u += 0x7fff + ((u >> 16) & 1);          // RNE to bf16
    return (unsigned short)(u >> 16);
}
__device__ __forceinline__ float bf2f(unsigned short h) {
    return __uint_as_float(((unsigned)h) << 16);
}

// ---------- row-normalize: emit bf16 hi/lo of xn + 1/||x|| ----------
__global__ __launch_bounds__(256) void rownorm_k(const float* __restrict__ x,
                                                 unsigned short* __restrict__ xnh,
                                                 unsigned short* __restrict__ xnl,
                                                 float* __restrict__ norminv) {
    int row = blockIdx.x;
    const float* xr = x + (size_t)row * IN_FT;
    float s = 0.f;
    for (int j = threadIdx.x; j < IN_FT; j += 256) { float v = xr[j]; s += v * v; }
    __shared__ float red[256];
    red[threadIdx.x] = s; __syncthreads();
    for (int off = 128; off > 0; off >>= 1) {
        if (threadIdx.x < off) red[threadIdx.x] += red[threadIdx.x + off];
        __syncthreads();
    }
    float inv = 1.0f / fmaxf(sqrtf(red[0]), 1e-12f);
    if (threadIdx.x == 0) norminv[row] = inv;
    for (int j = threadIdx.x; j < IN_FT; j += 256) {
        float v = xr[j] * inv;                 // same op fix_rows_k replays
        unsigned short hi = f2bf(v);
        unsigned short lo = f2bf(v - bf2f(hi));
        xnh[(size_t)row * IN_FT + j] = hi;
        xnl[(size_t)row * IN_FT + j] = lo;
    }
}

// ---------- approx cos via bf16x3 MFMA (err <= ~1.5e-5; selection guarded) ----------
// Fragment pattern identical to the verified proj_mfma_k: A/B lane l reads 8
// contiguous bf16 at row (l&15), k-offset 8*(l>>4); D col=l&15, row=(l>>4)*4+r.
__global__ __launch_bounds__(256) void cos_mfma_k(const unsigned short* __restrict__ xh,
                                                  const unsigned short* __restrict__ xl,
                                                  float* __restrict__ C) {
    int tid = threadIdx.x;
    int wave = tid >> 6, l = tid & 63;
    int wm = wave >> 1, wn = wave & 1;
    int m0 = blockIdx.y * 128 + wm * 64;
    int n0 = blockIdx.x * 128 + wn * 64;
    int lr = l & 15;
    int kq = (l >> 4) * 8;
    f32x4 acc[4][4] = {};
    for (int k0 = 0; k0 < IN_FT; k0 += 32) {
        s16x8 ah[4], al[4];
#pragma unroll
        for (int mi = 0; mi < 4; ++mi) {
            size_t ro = (size_t)(m0 + mi * 16 + lr) * IN_FT + k0 + kq;
            ah[mi] = *(const s16x8*)(xh + ro);
            al[mi] = *(const s16x8*)(xl + ro);
        }
#pragma unroll
        for (int ni = 0; ni < 4; ++ni) {
            size_t ro = (size_t)(n0 + ni * 16 + lr) * IN_FT + k0 + kq;
            s16x8 bh = *(const s16x8*)(xh + ro);
            s16x8 bl = *(const s16x8*)(xl + ro);
#pragma unroll
            for (int mi = 0; mi < 4; ++mi) {
                acc[mi][ni] = __builtin_amdgcn_mfma_f32_16x16x32_bf16(ah[mi], bh, acc[mi][ni], 0, 0, 0);
                acc[mi][ni] = __builtin_amdgcn_mfma_f32_16x16x32_bf16(ah[mi], bl, acc[mi][ni], 0, 0, 0);
                acc[mi][ni] = __builtin_amdgcn_mfma_f32_16x16x32_bf16(al[mi], bh, acc[mi][ni], 0, 0, 0);
            }
        }
    }
#pragma unroll
    for (int mi = 0; mi < 4; ++mi)
#pragma unroll
        for (int r = 0; r < 4; ++r) {
            int m = m0 + mi * 16 + (l >> 4) * 4 + r;
#pragma unroll
            for (int ni = 0; ni < 4; ++ni)
                C[(size_t)m * N + n0 + ni * 16 + lr] = acc[mi][ni][r];
        }
}

// ---------- per-row top-k on approx cos + ambiguity flagging ----------
// Selection comparator identical to all prior rounds. Rows where any value
// falls within GAPWIN of the 10th max (or of COS_THR) are flagged for exact
// recompute; candidates (10 selected + window extras) stored for fix_rows_k.
__global__ __launch_bounds__(256) void topk_mask_k(const float* __restrict__ cosm,
                                                   unsigned* __restrict__ maskT,
                                                   const float* __restrict__ w2,
                                                   const float* __restrict__ Hmat,
                                                   int* __restrict__ rlist,
                                                   float* __restrict__ rval,
                                                   int* __restrict__ rcnt,
                                                   int* __restrict__ cand,
                                                   int* __restrict__ candcnt,
                                                   int* __restrict__ flagrow) {
    int row = blockIdx.x;
    int tid = threadIdx.x;
    __shared__ unsigned char flag[N];
    __shared__ unsigned char extr[N];
    __shared__ float wbv[4];
    __shared__ int wbi[4];
    __shared__ int wcnt[4];
    __shared__ int basev;
    int lane = tid & 63, wid = tid >> 6;
    const float* crow = cosm + (size_t)row * N;
    float v[16];
    unsigned fl = 0;
#pragma unroll
    for (int q = 0; q < 4; ++q) {
        float4 f4 = *(const float4*)&crow[tid * 16 + q * 4];
        v[q * 4 + 0] = f4.x; v[q * 4 + 1] = f4.y;
        v[q * 4 + 2] = f4.z; v[q * 4 + 3] = f4.w;
    }
#pragma unroll
    for (int c = 0; c < 16; ++c)
        if (v[c] > COS_THR) fl |= 1u << c;
    float v10 = 0.f;
    for (int t = 0; t < COS_K; ++t) {
        float best = -INFINITY;
        int bidx = 0x7fffffff;
#pragma unroll
        for (int c = 0; c < 16; ++c)
            if (v[c] > best) { best = v[c]; bidx = tid * 16 + c; }
#pragma unroll
        for (int off = 32; off > 0; off >>= 1) {
            float v2 = __shfl_xor(best, off);
            int i2 = __shfl_xor(bidx, off);
            if (v2 > best || (v2 == best && i2 < bidx)) { best = v2; bidx = i2; }
        }
        __syncthreads();
        if (lane == 0) { wbv[wid] = best; wbi[wid] = bidx; }
        __syncthreads();
        float fb = wbv[0]; int fi = wbi[0];
#pragma unroll
        for (int w = 1; w < 4; ++w) {
            float v2 = wbv[w]; int i2 = wbi[w];
            if (v2 > fb || (v2 == fb && i2 < fi)) { fb = v2; fi = i2; }
        }
        if ((fi >> 4) == tid) {                // owning thread invalidates + flags
            v[fi & 15] = -INFINITY;
            fl |= 1u << (fi & 15);
        }
        if (tid == 0) cand[(size_t)row * CAP_C + t] = fi;
        v10 = fb;                              // after last pass: 10th max
    }
    // --- spill flags + ambiguity-window markers ---
#pragma unroll
    for (int c = 0; c < 16; ++c) {
        flag[tid * 16 + c] = (fl >> c) & 1;
        bool e = (v[c] > v10 - GAPWIN) ||      // extracted are -INF: excluded
                 (fabsf(v[c] - COS_THR) < GAPWIN);
        extr[tid * 16 + c] = e ? 1 : 0;
    }
    __syncthreads();
    // --- transposed bitmask ---
    for (int wdx = tid; wdx < NW; wdx += 256) {
        unsigned bits = 0;
#pragma unroll
        for (int b = 0; b < 32; ++b) bits |= (flag[wdx * 32 + b] ? 1u : 0u) << b;
        maskT[(size_t)wdx * N + row] = bits;
    }
    // --- row sparse list via ballot compaction (deterministic e-ascending) ---
    if (tid == 0) basev = 0;
    __syncthreads();
    for (int c = 0; c < 16; ++c) {
        int j = c * 256 + tid;
        bool f = flag[j] != 0;
        unsigned long long b = __ballot(f);
        if (lane == 0) wcnt[wid] = __popcll(b);
        __syncthreads();
        int off = basev;
        for (int w = 0; w < wid; ++w) off += wcnt[w];
        int pos = off + __popcll(b & ((1ull << lane) - 1ull));
        if (f && pos < CAP) {
            size_t ofs = (size_t)row * N + j;
            rlist[(size_t)row * CAP + pos] = j;
            rval[(size_t)row * CAP + pos] = w2[ofs] * Hmat[ofs];
        }
        __syncthreads();
        if (tid == 0) basev += wcnt[0] + wcnt[1] + wcnt[2] + wcnt[3];
        __syncthreads();
    }
    if (tid == 0) rcnt[row] = basev < CAP ? basev : CAP;
    // --- candidate extras (ascending j) + flag ---
    if (tid == 0) basev = 0;
    __syncthreads();
    for (int c = 0; c < 16; ++c) {
        int j = c * 256 + tid;
        bool f = extr[j] != 0;
        unsigned long long b = __ballot(f);
        if (lane == 0) wcnt[wid] = __popcll(b);
        __syncthreads();
        int off = basev;
        for (int w = 0; w < wid; ++w) off += wcnt[w];
        int pos = COS_K + off + __popcll(b & ((1ull << lane) - 1ull));
        if (f && pos < CAP_C) cand[(size_t)row * CAP_C + pos] = j;
        __syncthreads();
        if (tid == 0) basev += wcnt[0] + wcnt[1] + wcnt[2] + wcnt[3];
        __syncthreads();
    }
    if (tid == 0) {
        int tot = COS_K + basev;
        candcnt[row] = tot < CAP_C ? tot : CAP_C;
        flagrow[row] = (basev > 0) ? 1 : 0;
    }
}

// ---------- exact recompute for ambiguous rows (serial chain == prior rounds) ----------
__global__ __launch_bounds__(64) void fix_rows_k(const int* __restrict__ flagrow,
                                                 const int* __restrict__ candcnt,
                                                 const int* __restrict__ cand,
                                                 const float* __restrict__ x,
                                                 const float* __restrict__ norminv,
                                                 const float* __restrict__ cosm,
                                                 const float* __restrict__ w2,
                                                 const float* __restrict__ Hmat,
                                                 unsigned* __restrict__ maskT,
                                                 int* __restrict__ rlist,
                                                 float* __restrict__ rval,
                                                 int* __restrict__ rcnt) {
    int row = blockIdx.x;
    if (!flagrow[row]) return;
    int tid = threadIdx.x;                     // one wave
    __shared__ float exv[CAP_C];
    __shared__ int cj[CAP_C];
    __shared__ int sel[CAP_C];
    __shared__ unsigned char flg[N];
    int M = candcnt[row];
    if (tid < M) cj[tid] = cand[(size_t)row * CAP_C + tid];
    __syncthreads();
    if (tid < M) {
        int j = cj[tid];
        float invr = norminv[row], invj = norminv[j];
        const float* xr = x + (size_t)row * IN_FT;
        const float* xj = x + (size_t)j * IN_FT;
        float acc = 0.f;
        for (int k = 0; k < IN_FT; ++k)
            acc = fmaf(xr[k] * invr, xj[k] * invj, acc);   // exact chain of rounds 0-10
        exv[tid] = acc;
    }
    __syncthreads();
    if (tid < M) {
        float vv = exv[tid]; int j = cj[tid];
        int rank = 0;
        for (int m = 0; m < M; ++m) {
            float v2 = exv[m]; int j2 = cj[m];
            if (v2 > vv || (v2 == vv && j2 < j)) ++rank;   // np top_k tie-break
        }
        sel[tid] = (rank < COS_K) ? 1 : 0;
    }
    __syncthreads();
    const float* crow = cosm + (size_t)row * N;
    for (int j0 = tid; j0 < N; j0 += 64) {
        float av = crow[j0];
        int inc = -1;
        for (int m = 0; m < M; ++m) if (cj[m] == j0) { inc = m; break; }
        unsigned char f;
        if (inc >= 0) f = (exv[inc] > COS_THR) || sel[inc];
        else          f = (av > COS_THR);
        flg[j0] = f;
    }
    __syncthreads();
    for (int w = tid; w < NW; w += 64) {
        unsigned bits = 0;
#pragma unroll
        for (int b = 0; b < 32; ++b) bits |= (flg[w * 32 + b] ? 1u : 0u) << b;
        maskT[(size_t)w * N + row] = bits;
    }
    int cnt = 0;                               // single-wave ballot compaction
    for (int c = 0; c < 64; ++c) {
        int j = c * 64 + tid;
        bool f = flg[j] != 0;
        unsigned long long b = __ballot(f);
        int pos = cnt + __popcll(b & ((1ull << tid) - 1ull));
        if (f && pos < CAP) {
            size_t ofs = (size_t)row * N + j;
            rlist[(size_t)row * CAP + pos] = j;
            rval[(size_t)row * CAP + pos] = w2[ofs] * Hmat[ofs];
        }
        cnt += __popcll(b);
    }
    if (tid == 0) rcnt[row] = cnt < CAP ? cnt : CAP;
}

// ---------- split x and proj_w into bf16 (hi, lo) pairs ----------
__global__ __launch_bounds__(256) void cast_split_k(const float* __restrict__ x,
                                                    const float* __restrict__ w,
                                                    unsigned short* __restrict__ xh,
                                                    unsigned short* __restrict__ xl,
                                                    unsigned short* __restrict__ wh,
                                                    unsigned short* __restrict__ wl) {
    const int totx = (N * IN_FT) / 4;
    int idx = blockIdx.x * 256 + threadIdx.x;
    bool isx = idx < totx;
    int i4 = isx ? idx : idx - totx;
    float4 f = isx ? ((const float4*)x)[i4] : ((const float4*)w)[i4];
    ushort4 hi, lo;
    hi.x = f2bf(f.x); lo.x = f2bf(f.x - bf2f(hi.x));
    hi.y = f2bf(f.y); lo.y = f2bf(f.y - bf2f(hi.y));
    hi.z = f2bf(f.z); lo.z = f2bf(f.z - bf2f(hi.z));
    hi.w = f2bf(f.w); lo.w = f2bf(f.w - bf2f(hi.w));
    if (isx) { ((ushort4*)xh)[i4] = hi; ((ushort4*)xl)[i4] = lo; }
    else     { ((ushort4*)wh)[i4] = hi; ((ushort4*)wl)[i4] = lo; }
}

// ---------- h = x @ proj_w^T + b via bf16x3 MFMA ----------
__global__ __launch_bounds__(256) void proj_mfma_k(const unsigned short* __restrict__ xh,
                                                   const unsigned short* __restrict__ xl,
                                                   const unsigned short* __restrict__ wh,
                                                   const unsigned short* __restrict__ wl,
                                                   const float* __restrict__ bias,
                                                   float* __restrict__ h) {
    int tid = threadIdx.x;
    int wave = tid >> 6, l = tid & 63;
    int m0 = blockIdx.y * 64 + wave * 16;
    int n0 = blockIdx.x * 64;
    int lr = l & 15;
    int kq = (l >> 4) * 8;
    const unsigned short* pah = xh + (size_t)(m0 + lr) * IN_FT + kq;
    const unsigned short* pal = xl + (size_t)(m0 + lr) * IN_FT + kq;
    f32x4 acc[4] = {};
    for (int k0 = 0; k0 < IN_FT; k0 += 32) {
        s16x8 ah = *(const s16x8*)(pah + k0);
        s16x8 al = *(const s16x8*)(pal + k0);
#pragma unroll
        for (int g = 0; g < 4; ++g) {
            const unsigned short* pbh = wh + (size_t)(n0 + g * 16 + lr) * IN_FT + kq + k0;
            const unsigned short* pbl = wl + (size_t)(n0 + g * 16 + lr) * IN_FT + kq + k0;
            s16x8 bh = *(const s16x8*)pbh;
            s16x8 bl = *(const s16x8*)pbl;
            acc[g] = __builtin_amdgcn_mfma_f32_16x16x32_bf16(ah, bh, acc[g], 0, 0, 0);
            acc[g] = __builtin_amdgcn_mfma_f32_16x16x32_bf16(ah, bl, acc[g], 0, 0, 0);
            acc[g] = __builtin_amdgcn_mfma_f32_16x16x32_bf16(al, bh, acc[g], 0, 0, 0);
        }
    }
#pragma unroll
    for (int g = 0; g < 4; ++g)
#pragma unroll
        for (int r = 0; r < 4; ++r) {
            int m = m0 + (l >> 4) * 4 + r;
            int n = n0 + g * 16 + lr;
            h[(size_t)m * OUT_FT + n] = acc[g][r] + bias[n];
        }
}

// ---------- column build pass 1: per-(v-chunk, e) bit counts ----------
__global__ __launch_bounds__(256) void count_cols_k(const unsigned* __restrict__ maskT,
                                                    int* __restrict__ cnt16) {
    __shared__ unsigned ch[8][256];
    int tid = threadIdx.x;
    int eb = blockIdx.x, chunk = blockIdx.y;
    int wbase = eb * 8, v0 = chunk * 256;
#pragma unroll
    for (int i = 0; i < 8; ++i)
        ch[i][tid] = maskT[(size_t)(wbase + i) * N + v0 + tid];
    __syncthreads();
    int wl = tid >> 5, bp = tid & 31;
    int cnt = 0;
#pragma unroll 8
    for (int v = 0; v < 256; ++v) cnt += (ch[wl][v] >> bp) & 1;
    cnt16[chunk * N + eb * 256 + tid] = cnt;
}

// ---------- column build pass 2: fill at prefix offsets (deterministic) ----------
__global__ __launch_bounds__(256) void fill_cols_k(const unsigned* __restrict__ maskT,
                                                   const int* __restrict__ cnt16,
                                                   const float* __restrict__ w1,
                                                   const float* __restrict__ Hmat,
                                                   int* __restrict__ elist,
                                                   float* __restrict__ eval_,
                                                   int* __restrict__ ecnt) {
    __shared__ unsigned ch[8][256];
    int tid = threadIdx.x;
    int eb = blockIdx.x, chunk = blockIdx.y;
    int e = eb * 256 + tid;
    int wbase = eb * 8, v0 = chunk * 256;
#pragma unroll
    for (int i = 0; i < 8; ++i)
        ch[i][tid] = maskT[(size_t)(wbase + i) * N + v0 + tid];
    int pos = 0;
    for (int c = 0; c < chunk; ++c) pos += cnt16[c * N + e];
    __syncthreads();
    int wl = tid >> 5;
    unsigned bit = 1u << (tid & 31);
    for (int v = 0; v < 256; ++v) {
        if (ch[wl][v] & bit) {
            if (pos < CAP) {
                size_t ofs = (size_t)(v0 + v) * N + e;
                elist[(size_t)e * CAP + pos] = v0 + v;
                eval_[(size_t)e * CAP + pos] = w1[ofs] * Hmat[ofs];
            }
            ++pos;
        }
    }
    if (chunk == 15) ecnt[e] = pos < CAP ? pos : CAP;
}

// ---------- dst[i,:] = (1/max(sum|val|,eps)) * sum val*src[list,:] ----------
__global__ __launch_bounds__(256) void spmm_k(const int* __restrict__ list,
                                              const float* __restrict__ val,
                                              const int* __restrict__ cnt,
                                              const float* __restrict__ src,
                                              float* __restrict__ dst) {
    int i = blockIdx.x;
    int f2 = threadIdx.x;
    int c = cnt[i];
    float ssum = 0.f;
    for (int t = 0; t < c; ++t) ssum += fabsf(val[(size_t)i * CAP + t]);
    float acc0 = 0.f, acc1 = 0.f;
    for (int t = 0; t < c; ++t) {
        int j = list[(size_t)i * CAP + t];
        float a = val[(size_t)i * CAP + t];
        float2 s = *(const float2*)&src[(size_t)j * OUT_FT + f2 * 2];
        acc0 += a * s.x;
        acc1 += a * s.y;
    }
    float sc = 1.0f / fmaxf(ssum, EPSN);
    float2 o = make_float2(acc0 * sc, acc1 * sc);
    *(float2*)&dst[(size_t)i * OUT_FT + f2 * 2] = o;
}

extern "C" void kernel_launch(void* const* d_in, const int* in_sizes, int n_in,
                              void* d_out, int out_size, void* d_ws, size_t ws_size,
                              hipStream_t stream) {
    const float* x      = (const float*)d_in[0];   // [4096,512]
    const float* Hmat   = (const float*)d_in[1];   // [4096,4096]
    const float* proj_w = (const float*)d_in[2];   // [512,512]
    const float* proj_b = (const float*)d_in[3];   // [512]
    const float* w1     = (const float*)d_in[4];   // [4096,4096]
    const float* w2     = (const float*)d_in[5];   // [4096,4096]
    float* out = (float*)d_out;

    char* ws = (char*)d_ws;
    unsigned short* xnh   = (unsigned short*)(ws + 0);         // 4 MB
    unsigned short* xnl   = (unsigned short*)(ws + 4194304);   // 4 MB
    float*          cosm  = (float*)(ws + 8388608);            // 64 MB, dead after fix_rows
    int*            elist = (int*)  (ws + 8388608);            // 4 MB (aliases dead cos)
    float*          eval_ = (float*)(ws + 12582912);           // 4 MB (aliases dead cos)
    float*          h     = (float*)(ws + 25165824);           // 8 MB (aliases dead cos)
    float*          h2    = (float*)(ws + 33554432);           // 8 MB (aliases dead cos)
    unsigned short* xhi   = (unsigned short*)(ws + 41943040);  // 4 MB (aliases dead cos)
    unsigned short* xlo   = (unsigned short*)(ws + 46137344);  // 4 MB (aliases dead cos)
    unsigned short* whi   = (unsigned short*)(ws + 50331648);  // 512 KB (aliases dead cos)
    unsigned short* wlo   = (unsigned short*)(ws + 50855936);  // 512 KB (aliases dead cos)
    unsigned*       maskT = (unsigned*)(ws + 75497472);        // 2 MB
    int*            ecnt    = (int*)(ws + 77594624);           // 16 KB
    int*            rcnt    = (int*)(ws + 77611008);           // 16 KB
    float*          norminv = (float*)(ws + 77627392);         // 16 KB
    int*            flagrow = (int*)(ws + 77643776);           // 16 KB
    int*            candcnt = (int*)(ws + 77660160);           // 16 KB
    int*            rlist   = (int*)(ws + 77676544);           // 4 MB
    float*          rval    = (float*)(ws + 81870848);         // 4 MB
    int*            cnt16   = (int*)(ws + 86065152);           // 256 KB
    int*            cand    = (int*)(ws + 86327296);           // 512 KB [4096][32]

    // 1. norms + bf16 hi/lo of xn
    rownorm_k<<<N, 256, 0, stream>>>(x, xnh, xnl, norminv);
    // 2. approx cos via bf16x3 MFMA (full matrix)
    cos_mfma_k<<<dim3(N / 128, N / 128), 256, 0, stream>>>(xnh, xnl, cosm);
    // 3. top-k + threshold on approx; flag ambiguous rows
    topk_mask_k<<<N, 256, 0, stream>>>(cosm, maskT, w2, Hmat, rlist, rval, rcnt,
                                       cand, candcnt, flagrow);
    // 4. exact recompute + correction for flagged rows (needs cosm: before proj!)
    fix_rows_k<<<N, 64, 0, stream>>>(flagrow, candcnt, cand, x, norminv, cosm,
                                     w2, Hmat, maskT, rlist, rval, rcnt);
    // 5. h = x @ proj_w^T + proj_b (cos region now dead; h aliases it)
    cast_split_k<<<(N * IN_FT + OUT_FT * IN_FT) / 1024, 256, 0, stream>>>(
        x, proj_w, xhi, xlo, whi, wlo);
    proj_mfma_k<<<dim3(OUT_FT / 64, N / 64), 256, 0, stream>>>(xhi, xlo, whi, wlo, proj_b, h);
    // 6. column lists: count -> fill at prefix offsets
    count_cols_k<<<dim3(16, 16), 256, 0, stream>>>(maskT, cnt16);
    fill_cols_k<<<dim3(16, 16), 256, 0, stream>>>(maskT, cnt16, w1, Hmat, elist, eval_, ecnt);
    // 7. h2[e,:] = normalize . gather-sum over column lists
    spmm_k<<<N, 256, 0, stream>>>(elist, eval_, ecnt, h, h2);
    // 8. out[v,:] = normalize . gather-sum over row lists
    spmm_k<<<N, 256, 0, stream>>>(rlist, rval, rcnt, h2, out);
}

// Round 12
// 328.615 us; speedup vs baseline: 1.4517x; 1.4517x over previous
//
#include <hip/hip_runtime.h>
#include <hip/hip_bf16.h>
#include <math.h>

#define N 4096
#define IN_FT 512
#define OUT_FT 512
#define COS_THR 0.5f
#define COS_K 10
#define EPSN 1e-12f
#define CAP 256          // max stored nnz per row/col (actual ~10)
#define NW (N / 32)      // bitmask words per row
#define CAP_C 128        // candidate slots per flagged row
#define GAPWIN 2e-4f     // ambiguity window; bf16x3 error bound ~1.5e-5

typedef short s16x8 __attribute__((ext_vector_type(8)));
typedef float f32x4 __attribute__((ext_vector_type(4)));

__device__ __forceinline__ unsigned short f2bf(float f) {
    unsigned u = __float_as_uint(f);
    u += 0x7fff + ((u >> 16) & 1);          // RNE to bf16
    return (unsigned short)(u >> 16);
}
__device__ __forceinline__ float bf2f(unsigned short h) {
    return __uint_as_float(((unsigned)h) << 16);
}
__device__ __forceinline__ void gload_lds16(const void* g, void* l) {
    __builtin_amdgcn_global_load_lds(
        (const __attribute__((address_space(1))) void*)g,
        (__attribute__((address_space(3))) void*)l, 16, 0, 0);
}

// ---------- row-normalize: emit bf16 hi/lo of xn + 1/||x|| ----------
__global__ __launch_bounds__(256) void rownorm_k(const float* __restrict__ x,
                                                 unsigned short* __restrict__ xnh,
                                                 unsigned short* __restrict__ xnl,
                                                 float* __restrict__ norminv) {
    int row = blockIdx.x;
    const float* xr = x + (size_t)row * IN_FT;
    float s = 0.f;
    for (int j = threadIdx.x; j < IN_FT; j += 256) { float v = xr[j]; s += v * v; }
    __shared__ float red[256];
    red[threadIdx.x] = s; __syncthreads();
    for (int off = 128; off > 0; off >>= 1) {
        if (threadIdx.x < off) red[threadIdx.x] += red[threadIdx.x + off];
        __syncthreads();
    }
    float inv = 1.0f / fmaxf(sqrtf(red[0]), 1e-12f);
    if (threadIdx.x == 0) norminv[row] = inv;
    for (int j = threadIdx.x; j < IN_FT; j += 256) {
        float v = xr[j] * inv;                 // same op fix_rows_k replays
        unsigned short hi = f2bf(v);
        unsigned short lo = f2bf(v - bf2f(hi));
        xnh[(size_t)row * IN_FT + j] = hi;
        xnl[(size_t)row * IN_FT + j] = lo;
    }
}

// ---------- approx cos: bf16x3 via LDS-staged MFMA GEMM (m97 structure) ----------
// K-loop = 48 steps of 32: panels (A,B) = (hi,hi),(hi,lo),(lo,hi) = bf16x3.
// Double-buffered LDS, global_load_lds width 16, 4 waves each 64x64 output.
__global__ __launch_bounds__(256) void cos_gemm_k(const unsigned short* __restrict__ xh,
                                                  const unsigned short* __restrict__ xl,
                                                  float* __restrict__ C) {
    __shared__ __align__(16) unsigned short As[2][128 * 32];   // 8 KB each
    __shared__ __align__(16) unsigned short Bs[2][128 * 32];
    int tid = threadIdx.x;
    int wave = tid >> 6, l = tid & 63;
    int bi = blockIdx.y * 128, bj = blockIdx.x * 128;
    int wm = wave >> 1, wn = wave & 1;
    int lm0 = wm * 64, ln0 = wn * 64;
    int lr4 = l >> 2;                 // staging: row within 16-row group
    int lc4 = (l & 3) * 8;            // staging: col offset (bf16 elems, 16B)
    int lr = l & 15, kq = (l >> 4) * 8, lg = l >> 4;
    f32x4 acc[4][4] = {};
    int buf = 0;
    // prologue: stage K-step 0 (panel 0: hi,hi)
#pragma unroll
    for (int q = 0; q < 2; ++q) {
        int r0 = (wave + q * 4) * 16;
        gload_lds16(xh + (size_t)(bi + r0 + lr4) * IN_FT + lc4, &As[0][r0 * 32]);
        gload_lds16(xh + (size_t)(bj + r0 + lr4) * IN_FT + lc4, &Bs[0][r0 * 32]);
    }
    asm volatile("s_waitcnt vmcnt(0)" ::: "memory");
    __syncthreads();
    for (int kt = 0; kt < 48; ++kt) {
        if (kt + 1 < 48) {                    // issue next-step loads (stay in flight)
            int p = (kt + 1) >> 4;
            int kc = ((kt + 1) & 15) * 32;
            const unsigned short* sa = (p == 2) ? xl : xh;
            const unsigned short* sb = (p == 1) ? xl : xh;
#pragma unroll
            for (int q = 0; q < 2; ++q) {
                int r0 = (wave + q * 4) * 16;
                gload_lds16(sa + (size_t)(bi + r0 + lr4) * IN_FT + kc + lc4,
                            &As[buf ^ 1][r0 * 32]);
                gload_lds16(sb + (size_t)(bj + r0 + lr4) * IN_FT + kc + lc4,
                            &Bs[buf ^ 1][r0 * 32]);
            }
        }
        s16x8 a[4], b[4];
#pragma unroll
        for (int mi = 0; mi < 4; ++mi)
            a[mi] = *(const s16x8*)&As[buf][(lm0 + mi * 16 + lr) * 32 + kq];
#pragma unroll
        for (int ni = 0; ni < 4; ++ni)
            b[ni] = *(const s16x8*)&Bs[buf][(ln0 + ni * 16 + lr) * 32 + kq];
#pragma unroll
        for (int mi = 0; mi < 4; ++mi)
#pragma unroll
            for (int ni = 0; ni < 4; ++ni)
                acc[mi][ni] = __builtin_amdgcn_mfma_f32_16x16x32_bf16(a[mi], b[ni], acc[mi][ni], 0, 0, 0);
        asm volatile("s_waitcnt vmcnt(0)" ::: "memory");
        __syncthreads();
        buf ^= 1;
    }
    // epilogue: D layout col=l&15, row=(l>>4)*4+r -> 64B segments per 16 lanes
#pragma unroll
    for (int mi = 0; mi < 4; ++mi)
#pragma unroll
        for (int r = 0; r < 4; ++r) {
            int m = bi + lm0 + mi * 16 + lg * 4 + r;
#pragma unroll
            for (int ni = 0; ni < 4; ++ni)
                C[(size_t)m * N + bj + ln0 + ni * 16 + lr] = acc[mi][ni][r];
        }
}

// ---------- per-row top-k on approx cos; flag ambiguous rows (cheap) ----------
__global__ __launch_bounds__(256) void topk_mask_k(const float* __restrict__ cosm,
                                                   unsigned* __restrict__ maskT,
                                                   const float* __restrict__ w2,
                                                   const float* __restrict__ Hmat,
                                                   int* __restrict__ rlist,
                                                   float* __restrict__ rval,
                                                   int* __restrict__ rcnt,
                                                   int* __restrict__ flagrow,
                                                   float* __restrict__ v10row) {
    int row = blockIdx.x;
    int tid = threadIdx.x;
    __shared__ unsigned char flag[N];
    __shared__ float wbv[4];
    __shared__ int wbi[4];
    __shared__ int wcnt[4];
    __shared__ int basev;
    int lane = tid & 63, wid = tid >> 6;
    const float* crow = cosm + (size_t)row * N;
    float v[16];
    unsigned fl = 0;
#pragma unroll
    for (int q = 0; q < 4; ++q) {
        float4 f4 = *(const float4*)&crow[tid * 16 + q * 4];
        v[q * 4 + 0] = f4.x; v[q * 4 + 1] = f4.y;
        v[q * 4 + 2] = f4.z; v[q * 4 + 3] = f4.w;
    }
#pragma unroll
    for (int c = 0; c < 16; ++c)
        if (v[c] > COS_THR) fl |= 1u << c;
    float v10 = 0.f;
    for (int t = 0; t < COS_K; ++t) {
        float best = -INFINITY;
        int bidx = 0x7fffffff;
#pragma unroll
        for (int c = 0; c < 16; ++c)
            if (v[c] > best) { best = v[c]; bidx = tid * 16 + c; }
#pragma unroll
        for (int off = 32; off > 0; off >>= 1) {
            float v2 = __shfl_xor(best, off);
            int i2 = __shfl_xor(bidx, off);
            if (v2 > best || (v2 == best && i2 < bidx)) { best = v2; bidx = i2; }
        }
        __syncthreads();
        if (lane == 0) { wbv[wid] = best; wbi[wid] = bidx; }
        __syncthreads();
        float fb = wbv[0]; int fi = wbi[0];
#pragma unroll
        for (int w = 1; w < 4; ++w) {
            float v2 = wbv[w]; int i2 = wbi[w];
            if (v2 > fb || (v2 == fb && i2 < fi)) { fb = v2; fi = i2; }
        }
        if ((fi >> 4) == tid) {                // owning thread invalidates + flags
            v[fi & 15] = -INFINITY;
            fl |= 1u << (fi & 15);
        }
        v10 = fb;                              // last pass: 10th max
    }
#pragma unroll
    for (int c = 0; c < 16; ++c) flag[tid * 16 + c] = (fl >> c) & 1;
    __syncthreads();
    // transposed bitmask
    for (int wdx = tid; wdx < NW; wdx += 256) {
        unsigned bits = 0;
#pragma unroll
        for (int b = 0; b < 32; ++b) bits |= (flag[wdx * 32 + b] ? 1u : 0u) << b;
        maskT[(size_t)wdx * N + row] = bits;
    }
    // row sparse list (deterministic e-ascending ballot compaction)
    if (tid == 0) basev = 0;
    __syncthreads();
    for (int c = 0; c < 16; ++c) {
        int j = c * 256 + tid;
        bool f = flag[j] != 0;
        unsigned long long b = __ballot(f);
        if (lane == 0) wcnt[wid] = __popcll(b);
        __syncthreads();
        int off = basev;
        for (int w = 0; w < wid; ++w) off += wcnt[w];
        int pos = off + __popcll(b & ((1ull << lane) - 1ull));
        if (f && pos < CAP) {
            size_t ofs = (size_t)row * N + j;
            rlist[(size_t)row * CAP + pos] = j;
            rval[(size_t)row * CAP + pos] = w2[ofs] * Hmat[ofs];
        }
        __syncthreads();
        if (tid == 0) basev += wcnt[0] + wcnt[1] + wcnt[2] + wcnt[3];
        __syncthreads();
    }
    if (tid == 0) rcnt[row] = basev < CAP ? basev : CAP;
    // ambiguity flag: any remaining value near v10 or near threshold
    bool amb = false;
#pragma unroll
    for (int c = 0; c < 16; ++c) {
        float vc = v[c];                        // extracted are -INF
        if (vc > v10 - GAPWIN || fabsf(vc - COS_THR) < GAPWIN) amb = true;
    }
    unsigned long long ab = __ballot(amb);
    __syncthreads();
    if (lane == 0) wcnt[wid] = (ab != 0ull) ? 1 : 0;
    __syncthreads();
    if (tid == 0) {
        flagrow[row] = wcnt[0] | wcnt[1] | wcnt[2] | wcnt[3];
        v10row[row] = v10;
    }
}

// ---------- exact recompute for ambiguous rows (validated r11 chain) ----------
__global__ __launch_bounds__(256) void fix_rows_k(const int* __restrict__ flagrow,
                                                  const float* __restrict__ v10row,
                                                  const float* __restrict__ x,
                                                  const float* __restrict__ norminv,
                                                  const float* __restrict__ cosm,
                                                  const float* __restrict__ w2,
                                                  const float* __restrict__ Hmat,
                                                  unsigned* __restrict__ maskT,
                                                  int* __restrict__ rlist,
                                                  float* __restrict__ rval,
                                                  int* __restrict__ rcnt) {
    int row = blockIdx.x;
    if (!flagrow[row]) return;
    int tid = threadIdx.x;
    int lane = tid & 63, wid = tid >> 6;
    __shared__ unsigned char flg[N];
    __shared__ unsigned char cnd[N];
    __shared__ int cj[CAP_C];
    __shared__ float exv[CAP_C];
    __shared__ unsigned char sel[CAP_C];
    __shared__ int wcnt[4];
    __shared__ int basev;
    const float* crow = cosm + (size_t)row * N;
    float v[16];
#pragma unroll
    for (int q = 0; q < 4; ++q) {
        float4 f4 = *(const float4*)&crow[tid * 16 + q * 4];
        v[q * 4 + 0] = f4.x; v[q * 4 + 1] = f4.y;
        v[q * 4 + 2] = f4.z; v[q * 4 + 3] = f4.w;
    }
    float v10 = v10row[row];
#pragma unroll
    for (int c = 0; c < 16; ++c) {
        flg[tid * 16 + c] = (v[c] > COS_THR) ? 1 : 0;   // non-candidate default
        cnd[tid * 16 + c] = (v[c] > v10 - GAPWIN || fabsf(v[c] - COS_THR) < GAPWIN) ? 1 : 0;
    }
    if (tid == 0) basev = 0;
    __syncthreads();
    // candidate compaction (ascending j)
    for (int c = 0; c < 16; ++c) {
        int j = c * 256 + tid;
        bool f = cnd[j] != 0;
        unsigned long long b = __ballot(f);
        if (lane == 0) wcnt[wid] = __popcll(b);
        __syncthreads();
        int off = basev;
        for (int w = 0; w < wid; ++w) off += wcnt[w];
        int pos = off + __popcll(b & ((1ull << lane) - 1ull));
        if (f && pos < CAP_C) cj[pos] = j;
        __syncthreads();
        if (tid == 0) basev += wcnt[0] + wcnt[1] + wcnt[2] + wcnt[3];
        __syncthreads();
    }
    int M = basev < CAP_C ? basev : CAP_C;
    // exact dots (serial ascending-k fmaf chain, same as r11 verified)
    if (tid < M) {
        int j = cj[tid];
        float invr = norminv[row], invj = norminv[j];
        const float* xr = x + (size_t)row * IN_FT;
        const float* xj = x + (size_t)j * IN_FT;
        float acc = 0.f;
        for (int k = 0; k < IN_FT; ++k)
            acc = fmaf(xr[k] * invr, xj[k] * invj, acc);
        exv[tid] = acc;
    }
    __syncthreads();
    if (tid < M) {
        float vv = exv[tid]; int j = cj[tid];
        int rank = 0;
        for (int m = 0; m < M; ++m) {
            float v2 = exv[m]; int j2 = cj[m];
            if (v2 > vv || (v2 == vv && j2 < j)) ++rank;
        }
        sel[tid] = (rank < COS_K) ? 1 : 0;
    }
    __syncthreads();
    if (tid < M) flg[cj[tid]] = ((exv[tid] > COS_THR) || sel[tid]) ? 1 : 0;
    __syncthreads();
    // rewrite maskT row
    for (int wdx = tid; wdx < NW; wdx += 256) {
        unsigned bits = 0;
#pragma unroll
        for (int b = 0; b < 32; ++b) bits |= (flg[wdx * 32 + b] ? 1u : 0u) << b;
        maskT[(size_t)wdx * N + row] = bits;
    }
    // rewrite row sparse list
    if (tid == 0) basev = 0;
    __syncthreads();
    for (int c = 0; c < 16; ++c) {
        int j = c * 256 + tid;
        bool f = flg[j] != 0;
        unsigned long long b = __ballot(f);
        if (lane == 0) wcnt[wid] = __popcll(b);
        __syncthreads();
        int off = basev;
        for (int w = 0; w < wid; ++w) off += wcnt[w];
        int pos = off + __popcll(b & ((1ull << lane) - 1ull));
        if (f && pos < CAP) {
            size_t ofs = (size_t)row * N + j;
            rlist[(size_t)row * CAP + pos] = j;
            rval[(size_t)row * CAP + pos] = w2[ofs] * Hmat[ofs];
        }
        __syncthreads();
        if (tid == 0) basev += wcnt[0] + wcnt[1] + wcnt[2] + wcnt[3];
        __syncthreads();
    }
    if (tid == 0) rcnt[row] = basev < CAP ? basev : CAP;
}

// ---------- split x and proj_w into bf16 (hi, lo) pairs ----------
__global__ __launch_bounds__(256) void cast_split_k(const float* __restrict__ x,
                                                    const float* __restrict__ w,
                                                    unsigned short* __restrict__ xh,
                                                    unsigned short* __restrict__ xl,
                                                    unsigned short* __restrict__ wh,
                                                    unsigned short* __restrict__ wl) {
    const int totx = (N * IN_FT) / 4;
    int idx = blockIdx.x * 256 + threadIdx.x;
    bool isx = idx < totx;
    int i4 = isx ? idx : idx - totx;
    float4 f = isx ? ((const float4*)x)[i4] : ((const float4*)w)[i4];
    ushort4 hi, lo;
    hi.x = f2bf(f.x); lo.x = f2bf(f.x - bf2f(hi.x));
    hi.y = f2bf(f.y); lo.y = f2bf(f.y - bf2f(hi.y));
    hi.z = f2bf(f.z); lo.z = f2bf(f.z - bf2f(hi.z));
    hi.w = f2bf(f.w); lo.w = f2bf(f.w - bf2f(hi.w));
    if (isx) { ((ushort4*)xh)[i4] = hi; ((ushort4*)xl)[i4] = lo; }
    else     { ((ushort4*)wh)[i4] = hi; ((ushort4*)wl)[i4] = lo; }
}

// ---------- h = x @ proj_w^T + b via bf16x3 MFMA ----------
__global__ __launch_bounds__(256) void proj_mfma_k(const unsigned short* __restrict__ xh,
                                                   const unsigned short* __restrict__ xl,
                                                   const unsigned short* __restrict__ wh,
                                                   const unsigned short* __restrict__ wl,
                                                   const float* __restrict__ bias,
                                                   float* __restrict__ h) {
    int tid = threadIdx.x;
    int wave = tid >> 6, l = tid & 63;
    int m0 = blockIdx.y * 64 + wave * 16;
    int n0 = blockIdx.x * 64;
    int lr = l & 15;
    int kq = (l >> 4) * 8;
    const unsigned short* pah = xh + (size_t)(m0 + lr) * IN_FT + kq;
    const unsigned short* pal = xl + (size_t)(m0 + lr) * IN_FT + kq;
    f32x4 acc[4] = {};
    for (int k0 = 0; k0 < IN_FT; k0 += 32) {
        s16x8 ah = *(const s16x8*)(pah + k0);
        s16x8 al = *(const s16x8*)(pal + k0);
#pragma unroll
        for (int g = 0; g < 4; ++g) {
            const unsigned short* pbh = wh + (size_t)(n0 + g * 16 + lr) * IN_FT + kq + k0;
            const unsigned short* pbl = wl + (size_t)(n0 + g * 16 + lr) * IN_FT + kq + k0;
            s16x8 bh = *(const s16x8*)pbh;
            s16x8 bl = *(const s16x8*)pbl;
            acc[g] = __builtin_amdgcn_mfma_f32_16x16x32_bf16(ah, bh, acc[g], 0, 0, 0);
            acc[g] = __builtin_amdgcn_mfma_f32_16x16x32_bf16(ah, bl, acc[g], 0, 0, 0);
            acc[g] = __builtin_amdgcn_mfma_f32_16x16x32_bf16(al, bh, acc[g], 0, 0, 0);
        }
    }
#pragma unroll
    for (int g = 0; g < 4; ++g)
#pragma unroll
        for (int r = 0; r < 4; ++r) {
            int m = m0 + (l >> 4) * 4 + r;
            int n = n0 + g * 16 + lr;
            h[(size_t)m * OUT_FT + n] = acc[g][r] + bias[n];
        }
}

// ---------- column build pass 1: per-(v-chunk, e) bit counts ----------
__global__ __launch_bounds__(256) void count_cols_k(const unsigned* __restrict__ maskT,
                                                    int* __restrict__ cnt16) {
    __shared__ unsigned ch[8][256];
    int tid = threadIdx.x;
    int eb = blockIdx.x, chunk = blockIdx.y;
    int wbase = eb * 8, v0 = chunk * 256;
#pragma unroll
    for (int i = 0; i < 8; ++i)
        ch[i][tid] = maskT[(size_t)(wbase + i) * N + v0 + tid];
    __syncthreads();
    int wl = tid >> 5, bp = tid & 31;
    int cnt = 0;
#pragma unroll 8
    for (int v = 0; v < 256; ++v) cnt += (ch[wl][v] >> bp) & 1;
    cnt16[chunk * N + eb * 256 + tid] = cnt;
}

// ---------- column build pass 2: fill at prefix offsets (deterministic) ----------
__global__ __launch_bounds__(256) void fill_cols_k(const unsigned* __restrict__ maskT,
                                                   const int* __restrict__ cnt16,
                                                   const float* __restrict__ w1,
                                                   const float* __restrict__ Hmat,
                                                   int* __restrict__ elist,
                                                   float* __restrict__ eval_,
                                                   int* __restrict__ ecnt) {
    __shared__ unsigned ch[8][256];
    int tid = threadIdx.x;
    int eb = blockIdx.x, chunk = blockIdx.y;
    int e = eb * 256 + tid;
    int wbase = eb * 8, v0 = chunk * 256;
#pragma unroll
    for (int i = 0; i < 8; ++i)
        ch[i][tid] = maskT[(size_t)(wbase + i) * N + v0 + tid];
    int pos = 0;
    for (int c = 0; c < chunk; ++c) pos += cnt16[c * N + e];
    __syncthreads();
    int wl = tid >> 5;
    unsigned bit = 1u << (tid & 31);
    for (int v = 0; v < 256; ++v) {
        if (ch[wl][v] & bit) {
            if (pos < CAP) {
                size_t ofs = (size_t)(v0 + v) * N + e;
                elist[(size_t)e * CAP + pos] = v0 + v;
                eval_[(size_t)e * CAP + pos] = w1[ofs] * Hmat[ofs];
            }
            ++pos;
        }
    }
    if (chunk == 15) ecnt[e] = pos < CAP ? pos : CAP;
}

// ---------- dst[i,:] = (1/max(sum|val|,eps)) * sum val*src[list,:] ----------
__global__ __launch_bounds__(256) void spmm_k(const int* __restrict__ list,
                                              const float* __restrict__ val,
                                              const int* __restrict__ cnt,
                                              const float* __restrict__ src,
                                              float* __restrict__ dst) {
    int i = blockIdx.x;
    int f2 = threadIdx.x;
    int c = cnt[i];
    float ssum = 0.f;
    for (int t = 0; t < c; ++t) ssum += fabsf(val[(size_t)i * CAP + t]);
    float acc0 = 0.f, acc1 = 0.f;
    for (int t = 0; t < c; ++t) {
        int j = list[(size_t)i * CAP + t];
        float a = val[(size_t)i * CAP + t];
        float2 s = *(const float2*)&src[(size_t)j * OUT_FT + f2 * 2];
        acc0 += a * s.x;
        acc1 += a * s.y;
    }
    float sc = 1.0f / fmaxf(ssum, EPSN);
    float2 o = make_float2(acc0 * sc, acc1 * sc);
    *(float2*)&dst[(size_t)i * OUT_FT + f2 * 2] = o;
}

extern "C" void kernel_launch(void* const* d_in, const int* in_sizes, int n_in,
                              void* d_out, int out_size, void* d_ws, size_t ws_size,
                              hipStream_t stream) {
    const float* x      = (const float*)d_in[0];   // [4096,512]
    const float* Hmat   = (const float*)d_in[1];   // [4096,4096]
    const float* proj_w = (const float*)d_in[2];   // [512,512]
    const float* proj_b = (const float*)d_in[3];   // [512]
    const float* w1     = (const float*)d_in[4];   // [4096,4096]
    const float* w2     = (const float*)d_in[5];   // [4096,4096]
    float* out = (float*)d_out;

    char* ws = (char*)d_ws;
    unsigned short* xnh   = (unsigned short*)(ws + 0);         // 4 MB
    unsigned short* xnl   = (unsigned short*)(ws + 4194304);   // 4 MB
    float*          cosm  = (float*)(ws + 8388608);            // 64 MB, dead after fix_rows
    int*            elist = (int*)  (ws + 8388608);            // 4 MB (aliases dead cos)
    float*          eval_ = (float*)(ws + 12582912);           // 4 MB (aliases dead cos)
    float*          h     = (float*)(ws + 25165824);           // 8 MB (aliases dead cos)
    float*          h2    = (float*)(ws + 33554432);           // 8 MB (aliases dead cos)
    unsigned short* xhi   = (unsigned short*)(ws + 41943040);  // 4 MB (aliases dead cos)
    unsigned short* xlo   = (unsigned short*)(ws + 46137344);  // 4 MB (aliases dead cos)
    unsigned short* whi   = (unsigned short*)(ws + 50331648);  // 512 KB (aliases dead cos)
    unsigned short* wlo   = (unsigned short*)(ws + 50855936);  // 512 KB (aliases dead cos)
    unsigned*       maskT = (unsigned*)(ws + 75497472);        // 2 MB
    int*            ecnt    = (int*)(ws + 77594624);           // 16 KB
    int*            rcnt    = (int*)(ws + 77611008);           // 16 KB
    float*          norminv = (float*)(ws + 77627392);         // 16 KB
    int*            flagrow = (int*)(ws + 77643776);           // 16 KB
    float*          v10row  = (float*)(ws + 77660160);         // 16 KB
    int*            rlist   = (int*)(ws + 77676544);           // 4 MB
    float*          rval    = (float*)(ws + 81870848);         // 4 MB
    int*            cnt16   = (int*)(ws + 86065152);           // 256 KB

    // 1. norms + bf16 hi/lo of xn
    rownorm_k<<<N, 256, 0, stream>>>(x, xnh, xnl, norminv);
    // 2. approx cos via LDS-staged bf16x3 MFMA GEMM
    cos_gemm_k<<<dim3(N / 128, N / 128), 256, 0, stream>>>(xnh, xnl, cosm);
    // 3. top-k + threshold on approx; flag ambiguous rows
    topk_mask_k<<<N, 256, 0, stream>>>(cosm, maskT, w2, Hmat, rlist, rval, rcnt,
                                       flagrow, v10row);
    // 4. exact recompute for flagged rows (reads cosm: before proj aliases it)
    fix_rows_k<<<N, 256, 0, stream>>>(flagrow, v10row, x, norminv, cosm,
                                      w2, Hmat, maskT, rlist, rval, rcnt);
    // 5. h = x @ proj_w^T + proj_b (cos region now dead; h aliases it)
    cast_split_k<<<(N * IN_FT + OUT_FT * IN_FT) / 1024, 256, 0, stream>>>(
        x, proj_w, xhi, xlo, whi, wlo);
    proj_mfma_k<<<dim3(OUT_FT / 64, N / 64), 256, 0, stream>>>(xhi, xlo, whi, wlo, proj_b, h);
    // 6. column lists: count -> fill at prefix offsets
    count_cols_k<<<dim3(16, 16), 256, 0, stream>>>(maskT, cnt16);
    fill_cols_k<<<dim3(16, 16), 256, 0, stream>>>(maskT, cnt16, w1, Hmat, elist, eval_, ecnt);
    // 7. h2[e,:] = normalize . gather-sum over column lists
    spmm_k<<<N, 256, 0, stream>>>(elist, eval_, ecnt, h, h2);
    // 8. out[v,:] = normalize . gather-sum over row lists
    spmm_k<<<N, 256, 0, stream>>>(rlist, rval, rcnt, h2, out);
}

// Round 13
// 301.867 us; speedup vs baseline: 1.5803x; 1.0886x over previous
//
#include <hip/hip_runtime.h>
#include <hip/hip_bf16.h>
#include <math.h>

#define N 4096
#define IN_FT 512
#define OUT_FT 512
#define COS_THR 0.5f
#define COS_K 10
#define EPSN 1e-12f
#define CAP 256          // max stored nnz per row/col (actual ~10)
#define NW (N / 32)      // bitmask words per row
#define CAP_C 128        // candidate slots per flagged row
#define GAPWIN 2e-4f     // ambiguity window; bf16x3 error bound ~1.5e-5

typedef short s16x8 __attribute__((ext_vector_type(8)));
typedef float f32x4 __attribute__((ext_vector_type(4)));

__device__ __forceinline__ unsigned short f2bf(float f) {
    unsigned u = __float_as_uint(f);
    u += 0x7fff + ((u >> 16) & 1);          // RNE to bf16
    return (unsigned short)(u >> 16);
}
__device__ __forceinline__ float bf2f(unsigned short h) {
    return __uint_as_float(((unsigned)h) << 16);
}
__device__ __forceinline__ void gload_lds16(const void* g, void* l) {
    __builtin_amdgcn_global_load_lds(
        (const __attribute__((address_space(1))) void*)g,
        (__attribute__((address_space(3))) void*)l, 16, 0, 0);
}

// ---------- row-normalize: emit bf16 hi/lo of xn + 1/||x|| ----------
__global__ __launch_bounds__(256) void rownorm_k(const float* __restrict__ x,
                                                 unsigned short* __restrict__ xnh,
                                                 unsigned short* __restrict__ xnl,
                                                 float* __restrict__ norminv) {
    int row = blockIdx.x;
    const float* xr = x + (size_t)row * IN_FT;
    float s = 0.f;
    for (int j = threadIdx.x; j < IN_FT; j += 256) { float v = xr[j]; s += v * v; }
    __shared__ float red[256];
    red[threadIdx.x] = s; __syncthreads();
    for (int off = 128; off > 0; off >>= 1) {
        if (threadIdx.x < off) red[threadIdx.x] += red[threadIdx.x + off];
        __syncthreads();
    }
    float inv = 1.0f / fmaxf(sqrtf(red[0]), 1e-12f);
    if (threadIdx.x == 0) norminv[row] = inv;
    for (int j = threadIdx.x; j < IN_FT; j += 256) {
        float v = xr[j] * inv;                 // same op fix_rows_k replays
        unsigned short hi = f2bf(v);
        unsigned short lo = f2bf(v - bf2f(hi));
        xnh[(size_t)row * IN_FT + j] = hi;
        xnl[(size_t)row * IN_FT + j] = lo;
    }
}

// ---------- approx cos: bf16x3 via LDS-staged MFMA GEMM (m97 structure) ----------
__global__ __launch_bounds__(256) void cos_gemm_k(const unsigned short* __restrict__ xh,
                                                  const unsigned short* __restrict__ xl,
                                                  float* __restrict__ C) {
    __shared__ __align__(16) unsigned short As[2][128 * 32];
    __shared__ __align__(16) unsigned short Bs[2][128 * 32];
    int tid = threadIdx.x;
    int wave = tid >> 6, l = tid & 63;
    int bi = blockIdx.y * 128, bj = blockIdx.x * 128;
    int wm = wave >> 1, wn = wave & 1;
    int lm0 = wm * 64, ln0 = wn * 64;
    int lr4 = l >> 2;
    int lc4 = (l & 3) * 8;
    int lr = l & 15, kq = (l >> 4) * 8, lg = l >> 4;
    f32x4 acc[4][4] = {};
    int buf = 0;
#pragma unroll
    for (int q = 0; q < 2; ++q) {
        int r0 = (wave + q * 4) * 16;
        gload_lds16(xh + (size_t)(bi + r0 + lr4) * IN_FT + lc4, &As[0][r0 * 32]);
        gload_lds16(xh + (size_t)(bj + r0 + lr4) * IN_FT + lc4, &Bs[0][r0 * 32]);
    }
    asm volatile("s_waitcnt vmcnt(0)" ::: "memory");
    __syncthreads();
    for (int kt = 0; kt < 48; ++kt) {
        if (kt + 1 < 48) {
            int p = (kt + 1) >> 4;
            int kc = ((kt + 1) & 15) * 32;
            const unsigned short* sa = (p == 2) ? xl : xh;
            const unsigned short* sb = (p == 1) ? xl : xh;
#pragma unroll
            for (int q = 0; q < 2; ++q) {
                int r0 = (wave + q * 4) * 16;
                gload_lds16(sa + (size_t)(bi + r0 + lr4) * IN_FT + kc + lc4,
                            &As[buf ^ 1][r0 * 32]);
                gload_lds16(sb + (size_t)(bj + r0 + lr4) * IN_FT + kc + lc4,
                            &Bs[buf ^ 1][r0 * 32]);
            }
        }
        s16x8 a[4], b[4];
#pragma unroll
        for (int mi = 0; mi < 4; ++mi)
            a[mi] = *(const s16x8*)&As[buf][(lm0 + mi * 16 + lr) * 32 + kq];
#pragma unroll
        for (int ni = 0; ni < 4; ++ni)
            b[ni] = *(const s16x8*)&Bs[buf][(ln0 + ni * 16 + lr) * 32 + kq];
#pragma unroll
        for (int mi = 0; mi < 4; ++mi)
#pragma unroll
            for (int ni = 0; ni < 4; ++ni)
                acc[mi][ni] = __builtin_amdgcn_mfma_f32_16x16x32_bf16(a[mi], b[ni], acc[mi][ni], 0, 0, 0);
        asm volatile("s_waitcnt vmcnt(0)" ::: "memory");
        __syncthreads();
        buf ^= 1;
    }
#pragma unroll
    for (int mi = 0; mi < 4; ++mi)
#pragma unroll
        for (int r = 0; r < 4; ++r) {
            int m = bi + lm0 + mi * 16 + lg * 4 + r;
#pragma unroll
            for (int ni = 0; ni < 4; ++ni)
                C[(size_t)m * N + bj + ln0 + ni * 16 + lr] = acc[mi][ni][r];
        }
}

// ---------- per-row top-k on approx cos: wave-local top-10 + merge ----------
// Comparator everywhere = (value desc, index asc), the same total order as all
// prior rounds. Global top-10 is contained in the union of the 4 wave-local
// top-10s (any global winner ranks <=10 within its wave) -> selected SET
// identical. Non-destructive exm mask keeps v[] pristine for the ambiguity
// window check (same GAPWIN semantics as r11/r12 validated machinery).
__global__ __launch_bounds__(256) void topk_mask_k(const float* __restrict__ cosm,
                                                   unsigned* __restrict__ maskT,
                                                   const float* __restrict__ w2,
                                                   const float* __restrict__ Hmat,
                                                   int* __restrict__ rlist,
                                                   float* __restrict__ rval,
                                                   int* __restrict__ rcnt,
                                                   int* __restrict__ flagrow,
                                                   float* __restrict__ v10row) {
    int row = blockIdx.x;
    int tid = threadIdx.x;
    int lane = tid & 63, wid = tid >> 6;
    __shared__ float wv[4][10];
    __shared__ int   wi[4][10];
    __shared__ int   win[10];
    __shared__ float v10s;
    __shared__ int   wtot[4];
    __shared__ int   wamb[4];
    const float* crow = cosm + (size_t)row * N;
    float v[16];
    unsigned fl = 0;
#pragma unroll
    for (int q = 0; q < 4; ++q) {
        float4 f4 = *(const float4*)&crow[tid * 16 + q * 4];
        v[q * 4 + 0] = f4.x; v[q * 4 + 1] = f4.y;
        v[q * 4 + 2] = f4.z; v[q * 4 + 3] = f4.w;
    }
#pragma unroll
    for (int c = 0; c < 16; ++c)
        if (v[c] > COS_THR) fl |= 1u << c;
    // --- wave-local top-10 (shfl only, no barriers) ---
    unsigned exm = 0;
#pragma unroll
    for (int t = 0; t < COS_K; ++t) {
        float best = -INFINITY; int bidx = 0x7fffffff;
#pragma unroll
        for (int c = 0; c < 16; ++c)
            if (!((exm >> c) & 1) && v[c] > best) { best = v[c]; bidx = tid * 16 + c; }
#pragma unroll
        for (int off = 32; off > 0; off >>= 1) {
            float v2 = __shfl_xor(best, off);
            int   i2 = __shfl_xor(bidx, off);
            if (v2 > best || (v2 == best && i2 < bidx)) { best = v2; bidx = i2; }
        }
        if ((bidx >> 4) == tid) exm |= 1u << (bidx & 15);   // owner marks extracted
        if (lane == t) { wv[wid][t] = best; wi[wid][t] = bidx; }
    }
    __syncthreads();
    // --- merge 4x10 candidates on wave 0 (same total order) ---
    if (wid == 0) {
        float mv = -INFINITY; int mi = 0x7fffffff;
        if (lane < 40) { int g = lane / 10, s = lane - g * 10; mv = wv[g][s]; mi = wi[g][s]; }
        for (int t = 0; t < COS_K; ++t) {
            float best = mv; int bidx = mi;
#pragma unroll
            for (int off = 32; off > 0; off >>= 1) {
                float v2 = __shfl_xor(best, off);
                int   i2 = __shfl_xor(bidx, off);
                if (v2 > best || (v2 == best && i2 < bidx)) { best = v2; bidx = i2; }
            }
            if (mi == bidx) mv = -INFINITY;    // winner self-invalidates (indices unique)
            if (lane == 0) { win[t] = bidx; if (t == COS_K - 1) v10s = best; }
        }
    }
    __syncthreads();
    // --- selected mask, flags ---
    unsigned sel = 0;
#pragma unroll
    for (int t = 0; t < COS_K; ++t) {
        int wj = win[t];
        if ((wj >> 4) == tid) sel |= 1u << (wj & 15);
    }
    fl |= sel;
    float v10 = v10s;
    // --- maskT: thread owns 16 contiguous flags = half a word; shfl pair-combine ---
    unsigned flp = __shfl_xor(fl, 1);
    if (!(tid & 1))
        maskT[(size_t)(tid >> 1) * N + row] = (fl & 0xffffu) | (flp << 16);
    // --- ambiguity window (identical semantics: selected excluded) ---
    bool amb = false;
#pragma unroll
    for (int c = 0; c < 16; ++c) {
        if ((sel >> c) & 1) continue;
        float vc = v[c];
        if (vc > v10 - GAPWIN || fabsf(vc - COS_THR) < GAPWIN) amb = true;
    }
    unsigned long long ab = __ballot(amb);
    if (lane == 0) wamb[wid] = (ab != 0ull) ? 1 : 0;
    // --- row-list: per-thread popcount + wave scan (ascending-j preserved) ---
    int cnt = __popc(fl);
    int scan = cnt;
#pragma unroll
    for (int off = 1; off < 64; off <<= 1) {
        int nv = __shfl_up(scan, off);
        if (lane >= off) scan += nv;
    }
    if (lane == 63) wtot[wid] = scan;
    __syncthreads();
    int base = scan - cnt;
    for (int w = 0; w < wid; ++w) base += wtot[w];
    unsigned m = fl;
    int pos = base;
    while (m) {
        int c = __builtin_ctz(m); m &= m - 1;
        int j = tid * 16 + c;
        if (pos < CAP) {
            size_t ofs = (size_t)row * N + j;
            rlist[(size_t)row * CAP + pos] = j;
            rval[(size_t)row * CAP + pos] = w2[ofs] * Hmat[ofs];
        }
        ++pos;
    }
    if (tid == 0) {
        int tot = wtot[0] + wtot[1] + wtot[2] + wtot[3];
        rcnt[row] = tot < CAP ? tot : CAP;
        flagrow[row] = wamb[0] | wamb[1] | wamb[2] | wamb[3];
        v10row[row] = v10;
    }
}

// ---------- exact recompute for ambiguous rows (validated r11/r12 chain) ----------
__global__ __launch_bounds__(256) void fix_rows_k(const int* __restrict__ flagrow,
                                                  const float* __restrict__ v10row,
                                                  const float* __restrict__ x,
                                                  const float* __restrict__ norminv,
                                                  const float* __restrict__ cosm,
                                                  const float* __restrict__ w2,
                                                  const float* __restrict__ Hmat,
                                                  unsigned* __restrict__ maskT,
                                                  int* __restrict__ rlist,
                                                  float* __restrict__ rval,
                                                  int* __restrict__ rcnt) {
    int row = blockIdx.x;
    if (!flagrow[row]) return;
    int tid = threadIdx.x;
    int lane = tid & 63, wid = tid >> 6;
    __shared__ unsigned char flg[N];
    __shared__ unsigned char cnd[N];
    __shared__ int cj[CAP_C];
    __shared__ float exv[CAP_C];
    __shared__ unsigned char sel[CAP_C];
    __shared__ int wcnt[4];
    __shared__ int basev;
    const float* crow = cosm + (size_t)row * N;
    float v[16];
#pragma unroll
    for (int q = 0; q < 4; ++q) {
        float4 f4 = *(const float4*)&crow[tid * 16 + q * 4];
        v[q * 4 + 0] = f4.x; v[q * 4 + 1] = f4.y;
        v[q * 4 + 2] = f4.z; v[q * 4 + 3] = f4.w;
    }
    float v10 = v10row[row];
#pragma unroll
    for (int c = 0; c < 16; ++c) {
        flg[tid * 16 + c] = (v[c] > COS_THR) ? 1 : 0;
        cnd[tid * 16 + c] = (v[c] > v10 - GAPWIN || fabsf(v[c] - COS_THR) < GAPWIN) ? 1 : 0;
    }
    if (tid == 0) basev = 0;
    __syncthreads();
    for (int c = 0; c < 16; ++c) {
        int j = c * 256 + tid;
        bool f = cnd[j] != 0;
        unsigned long long b = __ballot(f);
        if (lane == 0) wcnt[wid] = __popcll(b);
        __syncthreads();
        int off = basev;
        for (int w = 0; w < wid; ++w) off += wcnt[w];
        int pos = off + __popcll(b & ((1ull << lane) - 1ull));
        if (f && pos < CAP_C) cj[pos] = j;
        __syncthreads();
        if (tid == 0) basev += wcnt[0] + wcnt[1] + wcnt[2] + wcnt[3];
        __syncthreads();
    }
    int M = basev < CAP_C ? basev : CAP_C;
    if (tid < M) {
        int j = cj[tid];
        float invr = norminv[row], invj = norminv[j];
        const float* xr = x + (size_t)row * IN_FT;
        const float* xj = x + (size_t)j * IN_FT;
        float acc = 0.f;
        for (int k = 0; k < IN_FT; ++k)
            acc = fmaf(xr[k] * invr, xj[k] * invj, acc);
        exv[tid] = acc;
    }
    __syncthreads();
    if (tid < M) {
        float vv = exv[tid]; int j = cj[tid];
        int rank = 0;
        for (int m = 0; m < M; ++m) {
            float v2 = exv[m]; int j2 = cj[m];
            if (v2 > vv || (v2 == vv && j2 < j)) ++rank;
        }
        sel[tid] = (rank < COS_K) ? 1 : 0;
    }
    __syncthreads();
    if (tid < M) flg[cj[tid]] = ((exv[tid] > COS_THR) || sel[tid]) ? 1 : 0;
    __syncthreads();
    for (int wdx = tid; wdx < NW; wdx += 256) {
        unsigned bits = 0;
#pragma unroll
        for (int b = 0; b < 32; ++b) bits |= (flg[wdx * 32 + b] ? 1u : 0u) << b;
        maskT[(size_t)wdx * N + row] = bits;
    }
    if (tid == 0) basev = 0;
    __syncthreads();
    for (int c = 0; c < 16; ++c) {
        int j = c * 256 + tid;
        bool f = flg[j] != 0;
        unsigned long long b = __ballot(f);
        if (lane == 0) wcnt[wid] = __popcll(b);
        __syncthreads();
        int off = basev;
        for (int w = 0; w < wid; ++w) off += wcnt[w];
        int pos = off + __popcll(b & ((1ull << lane) - 1ull));
        if (f && pos < CAP) {
            size_t ofs = (size_t)row * N + j;
            rlist[(size_t)row * CAP + pos] = j;
            rval[(size_t)row * CAP + pos] = w2[ofs] * Hmat[ofs];
        }
        __syncthreads();
        if (tid == 0) basev += wcnt[0] + wcnt[1] + wcnt[2] + wcnt[3];
        __syncthreads();
    }
    if (tid == 0) rcnt[row] = basev < CAP ? basev : CAP;
}

// ---------- split x and proj_w into bf16 (hi, lo) pairs ----------
__global__ __launch_bounds__(256) void cast_split_k(const float* __restrict__ x,
                                                    const float* __restrict__ w,
                                                    unsigned short* __restrict__ xh,
                                                    unsigned short* __restrict__ xl,
                                                    unsigned short* __restrict__ wh,
                                                    unsigned short* __restrict__ wl) {
    const int totx = (N * IN_FT) / 4;
    int idx = blockIdx.x * 256 + threadIdx.x;
    bool isx = idx < totx;
    int i4 = isx ? idx : idx - totx;
    float4 f = isx ? ((const float4*)x)[i4] : ((const float4*)w)[i4];
    ushort4 hi, lo;
    hi.x = f2bf(f.x); lo.x = f2bf(f.x - bf2f(hi.x));
    hi.y = f2bf(f.y); lo.y = f2bf(f.y - bf2f(hi.y));
    hi.z = f2bf(f.z); lo.z = f2bf(f.z - bf2f(hi.z));
    hi.w = f2bf(f.w); lo.w = f2bf(f.w - bf2f(hi.w));
    if (isx) { ((ushort4*)xh)[i4] = hi; ((ushort4*)xl)[i4] = lo; }
    else     { ((ushort4*)wh)[i4] = hi; ((ushort4*)wl)[i4] = lo; }
}

// ---------- h = x @ proj_w^T + b via bf16x3 MFMA ----------
__global__ __launch_bounds__(256) void proj_mfma_k(const unsigned short* __restrict__ xh,
                                                   const unsigned short* __restrict__ xl,
                                                   const unsigned short* __restrict__ wh,
                                                   const unsigned short* __restrict__ wl,
                                                   const float* __restrict__ bias,
                                                   float* __restrict__ h) {
    int tid = threadIdx.x;
    int wave = tid >> 6, l = tid & 63;
    int m0 = blockIdx.y * 64 + wave * 16;
    int n0 = blockIdx.x * 64;
    int lr = l & 15;
    int kq = (l >> 4) * 8;
    const unsigned short* pah = xh + (size_t)(m0 + lr) * IN_FT + kq;
    const unsigned short* pal = xl + (size_t)(m0 + lr) * IN_FT + kq;
    f32x4 acc[4] = {};
    for (int k0 = 0; k0 < IN_FT; k0 += 32) {
        s16x8 ah = *(const s16x8*)(pah + k0);
        s16x8 al = *(const s16x8*)(pal + k0);
#pragma unroll
        for (int g = 0; g < 4; ++g) {
            const unsigned short* pbh = wh + (size_t)(n0 + g * 16 + lr) * IN_FT + kq + k0;
            const unsigned short* pbl = wl + (size_t)(n0 + g * 16 + lr) * IN_FT + kq + k0;
            s16x8 bh = *(const s16x8*)pbh;
            s16x8 bl = *(const s16x8*)pbl;
            acc[g] = __builtin_amdgcn_mfma_f32_16x16x32_bf16(ah, bh, acc[g], 0, 0, 0);
            acc[g] = __builtin_amdgcn_mfma_f32_16x16x32_bf16(ah, bl, acc[g], 0, 0, 0);
            acc[g] = __builtin_amdgcn_mfma_f32_16x16x32_bf16(al, bh, acc[g], 0, 0, 0);
        }
    }
#pragma unroll
    for (int g = 0; g < 4; ++g)
#pragma unroll
        for (int r = 0; r < 4; ++r) {
            int m = m0 + (l >> 4) * 4 + r;
            int n = n0 + g * 16 + lr;
            h[(size_t)m * OUT_FT + n] = acc[g][r] + bias[n];
        }
}

// ---------- column build pass 1: per-(v-chunk, e) bit counts ----------
__global__ __launch_bounds__(256) void count_cols_k(const unsigned* __restrict__ maskT,
                                                    int* __restrict__ cnt16) {
    __shared__ unsigned ch[8][256];
    int tid = threadIdx.x;
    int eb = blockIdx.x, chunk = blockIdx.y;
    int wbase = eb * 8, v0 = chunk * 256;
#pragma unroll
    for (int i = 0; i < 8; ++i)
        ch[i][tid] = maskT[(size_t)(wbase + i) * N + v0 + tid];
    __syncthreads();
    int wl = tid >> 5, bp = tid & 31;
    int cnt = 0;
#pragma unroll 8
    for (int v = 0; v < 256; ++v) cnt += (ch[wl][v] >> bp) & 1;
    cnt16[chunk * N + eb * 256 + tid] = cnt;
}

// ---------- column build pass 2: fill at prefix offsets (deterministic) ----------
__global__ __launch_bounds__(256) void fill_cols_k(const unsigned* __restrict__ maskT,
                                                   const int* __restrict__ cnt16,
                                                   const float* __restrict__ w1,
                                                   const float* __restrict__ Hmat,
                                                   int* __restrict__ elist,
                                                   float* __restrict__ eval_,
                                                   int* __restrict__ ecnt) {
    __shared__ unsigned ch[8][256];
    int tid = threadIdx.x;
    int eb = blockIdx.x, chunk = blockIdx.y;
    int e = eb * 256 + tid;
    int wbase = eb * 8, v0 = chunk * 256;
#pragma unroll
    for (int i = 0; i < 8; ++i)
        ch[i][tid] = maskT[(size_t)(wbase + i) * N + v0 + tid];
    int pos = 0;
    for (int c = 0; c < chunk; ++c) pos += cnt16[c * N + e];
    __syncthreads();
    int wl = tid >> 5;
    unsigned bit = 1u << (tid & 31);
    for (int v = 0; v < 256; ++v) {
        if (ch[wl][v] & bit) {
            if (pos < CAP) {
                size_t ofs = (size_t)(v0 + v) * N + e;
                elist[(size_t)e * CAP + pos] = v0 + v;
                eval_[(size_t)e * CAP + pos] = w1[ofs] * Hmat[ofs];
            }
            ++pos;
        }
    }
    if (chunk == 15) ecnt[e] = pos < CAP ? pos : CAP;
}

// ---------- dst[i,:] = (1/max(sum|val|,eps)) * sum val*src[list,:] ----------
__global__ __launch_bounds__(256) void spmm_k(const int* __restrict__ list,
                                              const float* __restrict__ val,
                                              const int* __restrict__ cnt,
                                              const float* __restrict__ src,
                                              float* __restrict__ dst) {
    int i = blockIdx.x;
    int f2 = threadIdx.x;
    int c = cnt[i];
    float ssum = 0.f;
    for (int t = 0; t < c; ++t) ssum += fabsf(val[(size_t)i * CAP + t]);
    float acc0 = 0.f, acc1 = 0.f;
    for (int t = 0; t < c; ++t) {
        int j = list[(size_t)i * CAP + t];
        float a = val[(size_t)i * CAP + t];
        float2 s = *(const float2*)&src[(size_t)j * OUT_FT + f2 * 2];
        acc0 += a * s.x;
        acc1 += a * s.y;
    }
    float sc = 1.0f / fmaxf(ssum, EPSN);
    float2 o = make_float2(acc0 * sc, acc1 * sc);
    *(float2*)&dst[(size_t)i * OUT_FT + f2 * 2] = o;
}

extern "C" void kernel_launch(void* const* d_in, const int* in_sizes, int n_in,
                              void* d_out, int out_size, void* d_ws, size_t ws_size,
                              hipStream_t stream) {
    const float* x      = (const float*)d_in[0];   // [4096,512]
    const float* Hmat   = (const float*)d_in[1];   // [4096,4096]
    const float* proj_w = (const float*)d_in[2];   // [512,512]
    const float* proj_b = (const float*)d_in[3];   // [512]
    const float* w1     = (const float*)d_in[4];   // [4096,4096]
    const float* w2     = (const float*)d_in[5];   // [4096,4096]
    float* out = (float*)d_out;

    char* ws = (char*)d_ws;
    unsigned short* xnh   = (unsigned short*)(ws + 0);         // 4 MB
    unsigned short* xnl   = (unsigned short*)(ws + 4194304);   // 4 MB
    float*          cosm  = (float*)(ws + 8388608);            // 64 MB, dead after fix_rows
    int*            elist = (int*)  (ws + 8388608);            // 4 MB (aliases dead cos)
    float*          eval_ = (float*)(ws + 12582912);           // 4 MB (aliases dead cos)
    float*          h     = (float*)(ws + 25165824);           // 8 MB (aliases dead cos)
    float*          h2    = (float*)(ws + 33554432);           // 8 MB (aliases dead cos)
    unsigned short* xhi   = (unsigned short*)(ws + 41943040);  // 4 MB (aliases dead cos)
    unsigned short* xlo   = (unsigned short*)(ws + 46137344);  // 4 MB (aliases dead cos)
    unsigned short* whi   = (unsigned short*)(ws + 50331648);  // 512 KB (aliases dead cos)
    unsigned short* wlo   = (unsigned short*)(ws + 50855936);  // 512 KB (aliases dead cos)
    unsigned*       maskT = (unsigned*)(ws + 75497472);        // 2 MB
    int*            ecnt    = (int*)(ws + 77594624);           // 16 KB
    int*            rcnt    = (int*)(ws + 77611008);           // 16 KB
    float*          norminv = (float*)(ws + 77627392);         // 16 KB
    int*            flagrow = (int*)(ws + 77643776);           // 16 KB
    float*          v10row  = (float*)(ws + 77660160);         // 16 KB
    int*            rlist   = (int*)(ws + 77676544);           // 4 MB
    float*          rval    = (float*)(ws + 81870848);         // 4 MB
    int*            cnt16   = (int*)(ws + 86065152);           // 256 KB

    // 1. norms + bf16 hi/lo of xn
    rownorm_k<<<N, 256, 0, stream>>>(x, xnh, xnl, norminv);
    // 2. approx cos via LDS-staged bf16x3 MFMA GEMM
    cos_gemm_k<<<dim3(N / 128, N / 128), 256, 0, stream>>>(xnh, xnl, cosm);
    // 3. top-k + threshold on approx; flag ambiguous rows (barrier-free selection)
    topk_mask_k<<<N, 256, 0, stream>>>(cosm, maskT, w2, Hmat, rlist, rval, rcnt,
                                       flagrow, v10row);
    // 4. exact recompute for flagged rows (reads cosm: before proj aliases it)
    fix_rows_k<<<N, 256, 0, stream>>>(flagrow, v10row, x, norminv, cosm,
                                      w2, Hmat, maskT, rlist, rval, rcnt);
    // 5. h = x @ proj_w^T + proj_b (cos region now dead; h aliases it)
    cast_split_k<<<(N * IN_FT + OUT_FT * IN_FT) / 1024, 256, 0, stream>>>(
        x, proj_w, xhi, xlo, whi, wlo);
    proj_mfma_k<<<dim3(OUT_FT / 64, N / 64), 256, 0, stream>>>(xhi, xlo, whi, wlo, proj_b, h);
    // 6. column lists: count -> fill at prefix offsets
    count_cols_k<<<dim3(16, 16), 256, 0, stream>>>(maskT, cnt16);
    fill_cols_k<<<dim3(16, 16), 256, 0, stream>>>(maskT, cnt16, w1, Hmat, elist, eval_, ecnt);
    // 7. h2[e,:] = normalize . gather-sum over column lists
    spmm_k<<<N, 256, 0, stream>>>(elist, eval_, ecnt, h, h2);
    // 8. out[v,:] = normalize . gather-sum over row lists
    spmm_k<<<N, 256, 0, stream>>>(rlist, rval, rcnt, h2, out);
}

// Round 14
// 296.333 us; speedup vs baseline: 1.6098x; 1.0187x over previous
//
#include <hip/hip_runtime.h>
#include <hip/hip_bf16.h>
#include <math.h>

#define N 4096
#define IN_FT 512
#define OUT_FT 512
#define COS_THR 0.5f
#define COS_K 10
#define EPSN 1e-12f
#define CAP 256          // max stored nnz per row/col (actual ~10)
#define NW (N / 32)      // bitmask words per row
#define CAP_C 128        // candidate slots per flagged row
#define GAPWIN 2e-4f     // ambiguity window; bf16x3 error ~1.5e-5 + mirror ulp
#define CNB 32           // 128-blocks per side

typedef short s16x8 __attribute__((ext_vector_type(8)));
typedef float f32x4 __attribute__((ext_vector_type(4)));

__device__ __forceinline__ unsigned short f2bf(float f) {
    unsigned u = __float_as_uint(f);
    u += 0x7fff + ((u >> 16) & 1);          // RNE to bf16
    return (unsigned short)(u >> 16);
}
__device__ __forceinline__ float bf2f(unsigned short h) {
    return __uint_as_float(((unsigned)h) << 16);
}
__device__ __forceinline__ void gload_lds16(const void* g, void* l) {
    __builtin_amdgcn_global_load_lds(
        (const __attribute__((address_space(1))) void*)g,
        (__attribute__((address_space(3))) void*)l, 16, 0, 0);
}

// ---------- row-normalize: emit bf16 hi/lo of xn + 1/||x|| ----------
__global__ __launch_bounds__(256) void rownorm_k(const float* __restrict__ x,
                                                 unsigned short* __restrict__ xnh,
                                                 unsigned short* __restrict__ xnl,
                                                 float* __restrict__ norminv) {
    int row = blockIdx.x;
    const float* xr = x + (size_t)row * IN_FT;
    float s = 0.f;
    for (int j = threadIdx.x; j < IN_FT; j += 256) { float v = xr[j]; s += v * v; }
    __shared__ float red[256];
    red[threadIdx.x] = s; __syncthreads();
    for (int off = 128; off > 0; off >>= 1) {
        if (threadIdx.x < off) red[threadIdx.x] += red[threadIdx.x + off];
        __syncthreads();
    }
    float inv = 1.0f / fmaxf(sqrtf(red[0]), 1e-12f);
    if (threadIdx.x == 0) norminv[row] = inv;
    for (int j = threadIdx.x; j < IN_FT; j += 256) {
        float v = xr[j] * inv;                 // same op fix_rows_k replays
        unsigned short hi = f2bf(v);
        unsigned short lo = f2bf(v - bf2f(hi));
        xnh[(size_t)row * IN_FT + j] = hi;
        xnl[(size_t)row * IN_FT + j] = lo;
    }
}

// ---------- approx cos: bf16x3 MFMA GEMM, upper-tri blocks + fused mirror ----------
// LDS chunk-XOR swizzle (rule #21): global_load_lds dest is linear; the GLOBAL
// source chunk is pre-swizzled (c ^ (row&3)) and the fragment read applies the
// same XOR -> quad-groups spread over 4 bank-groups (8-way -> 4-way conflict).
// Mirror store: same per-k products (IEEE mul commutes), panel order differs
// by ~1 ulp vs full computation — far inside GAPWIN; guard handles the rest.
__global__ __launch_bounds__(256) void cos_gemm_k(const unsigned short* __restrict__ xh,
                                                  const unsigned short* __restrict__ xl,
                                                  float* __restrict__ C) {
    __shared__ __align__(16) unsigned short As[2][128 * 32];
    __shared__ __align__(16) unsigned short Bs[2][128 * 32];
    int t = blockIdx.x;                        // 0 .. 527
    int by = 0;
    while (t >= CNB - by) { t -= CNB - by; ++by; }
    int bx = by + t;                           // by <= bx
    int tid = threadIdx.x;
    int wave = tid >> 6, l = tid & 63;
    int bi = by * 128, bj = bx * 128;
    int wm = wave >> 1, wn = wave & 1;
    int lm0 = wm * 64, ln0 = wn * 64;
    int lr4 = l >> 2;                          // staging dest row within 16-group
    int lc4s = (((l & 3) ^ ((l >> 2) & 3)) * 8); // swizzled SOURCE chunk (elements)
    int lr = l & 15, lg = l >> 4;
    int kqs = (((l >> 4) ^ (l & 3)) * 8);      // swizzled fragment-read chunk
    f32x4 acc[4][4] = {};
    int buf = 0;
#pragma unroll
    for (int q = 0; q < 2; ++q) {
        int r0 = (wave + q * 4) * 16;
        gload_lds16(xh + (size_t)(bi + r0 + lr4) * IN_FT + lc4s, &As[0][r0 * 32]);
        gload_lds16(xh + (size_t)(bj + r0 + lr4) * IN_FT + lc4s, &Bs[0][r0 * 32]);
    }
    asm volatile("s_waitcnt vmcnt(0)" ::: "memory");
    __syncthreads();
    for (int kt = 0; kt < 48; ++kt) {
        if (kt + 1 < 48) {                     // issue next-step loads
            int p = (kt + 1) >> 4;
            int kc = ((kt + 1) & 15) * 32;
            const unsigned short* sa = (p == 2) ? xl : xh;
            const unsigned short* sb = (p == 1) ? xl : xh;
#pragma unroll
            for (int q = 0; q < 2; ++q) {
                int r0 = (wave + q * 4) * 16;
                gload_lds16(sa + (size_t)(bi + r0 + lr4) * IN_FT + kc + lc4s,
                            &As[buf ^ 1][r0 * 32]);
                gload_lds16(sb + (size_t)(bj + r0 + lr4) * IN_FT + kc + lc4s,
                            &Bs[buf ^ 1][r0 * 32]);
            }
        }
        s16x8 a[4], b[4];
#pragma unroll
        for (int mi = 0; mi < 4; ++mi)
            a[mi] = *(const s16x8*)&As[buf][(lm0 + mi * 16 + lr) * 32 + kqs];
#pragma unroll
        for (int ni = 0; ni < 4; ++ni)
            b[ni] = *(const s16x8*)&Bs[buf][(ln0 + ni * 16 + lr) * 32 + kqs];
#pragma unroll
        for (int mi = 0; mi < 4; ++mi)
#pragma unroll
            for (int ni = 0; ni < 4; ++ni)
                acc[mi][ni] = __builtin_amdgcn_mfma_f32_16x16x32_bf16(a[mi], b[ni], acc[mi][ni], 0, 0, 0);
        asm volatile("s_waitcnt vmcnt(0)" ::: "memory");
        __syncthreads();
        buf ^= 1;
    }
    // upper block store: D layout col=l&15, row=lg*4+r
#pragma unroll
    for (int mi = 0; mi < 4; ++mi)
#pragma unroll
        for (int r = 0; r < 4; ++r) {
            int m = bi + lm0 + mi * 16 + lg * 4 + r;
#pragma unroll
            for (int ni = 0; ni < 4; ++ni)
                C[(size_t)m * N + bj + ln0 + ni * 16 + lr] = acc[mi][ni][r];
        }
    // mirrored block store: 4 contiguous rows per acc quad -> aligned float4
    if (bx != by) {
#pragma unroll
        for (int ni = 0; ni < 4; ++ni) {
            int cc = bj + ln0 + ni * 16 + lr;
#pragma unroll
            for (int mi = 0; mi < 4; ++mi) {
                float4 s = make_float4(acc[mi][ni][0], acc[mi][ni][1],
                                       acc[mi][ni][2], acc[mi][ni][3]);
                *(float4*)&C[(size_t)cc * N + bi + lm0 + mi * 16 + lg * 4] = s;
            }
        }
    }
}

// ---------- per-row top-k on approx cos: wave-local top-10 + merge ----------
__global__ __launch_bounds__(256) void topk_mask_k(const float* __restrict__ cosm,
                                                   unsigned* __restrict__ maskT,
                                                   const float* __restrict__ w2,
                                                   const float* __restrict__ Hmat,
                                                   int* __restrict__ rlist,
                                                   float* __restrict__ rval,
                                                   int* __restrict__ rcnt,
                                                   int* __restrict__ flagrow,
                                                   float* __restrict__ v10row) {
    int row = blockIdx.x;
    int tid = threadIdx.x;
    int lane = tid & 63, wid = tid >> 6;
    __shared__ float wv[4][10];
    __shared__ int   wi[4][10];
    __shared__ int   win[10];
    __shared__ float v10s;
    __shared__ int   wtot[4];
    __shared__ int   wamb[4];
    const float* crow = cosm + (size_t)row * N;
    float v[16];
    unsigned fl = 0;
#pragma unroll
    for (int q = 0; q < 4; ++q) {
        float4 f4 = *(const float4*)&crow[tid * 16 + q * 4];
        v[q * 4 + 0] = f4.x; v[q * 4 + 1] = f4.y;
        v[q * 4 + 2] = f4.z; v[q * 4 + 3] = f4.w;
    }
#pragma unroll
    for (int c = 0; c < 16; ++c)
        if (v[c] > COS_THR) fl |= 1u << c;
    // wave-local top-10 (shfl only)
    unsigned exm = 0;
#pragma unroll
    for (int t = 0; t < COS_K; ++t) {
        float best = -INFINITY; int bidx = 0x7fffffff;
#pragma unroll
        for (int c = 0; c < 16; ++c)
            if (!((exm >> c) & 1) && v[c] > best) { best = v[c]; bidx = tid * 16 + c; }
#pragma unroll
        for (int off = 32; off > 0; off >>= 1) {
            float v2 = __shfl_xor(best, off);
            int   i2 = __shfl_xor(bidx, off);
            if (v2 > best || (v2 == best && i2 < bidx)) { best = v2; bidx = i2; }
        }
        if ((bidx >> 4) == tid) exm |= 1u << (bidx & 15);
        if (lane == t) { wv[wid][t] = best; wi[wid][t] = bidx; }
    }
    __syncthreads();
    // merge 4x10 on wave 0 (same total order)
    if (wid == 0) {
        float mv = -INFINITY; int mi = 0x7fffffff;
        if (lane < 40) { int g = lane / 10, s = lane - g * 10; mv = wv[g][s]; mi = wi[g][s]; }
        for (int t = 0; t < COS_K; ++t) {
            float best = mv; int bidx = mi;
#pragma unroll
            for (int off = 32; off > 0; off >>= 1) {
                float v2 = __shfl_xor(best, off);
                int   i2 = __shfl_xor(bidx, off);
                if (v2 > best || (v2 == best && i2 < bidx)) { best = v2; bidx = i2; }
            }
            if (mi == bidx) mv = -INFINITY;
            if (lane == 0) { win[t] = bidx; if (t == COS_K - 1) v10s = best; }
        }
    }
    __syncthreads();
    unsigned sel = 0;
#pragma unroll
    for (int t = 0; t < COS_K; ++t) {
        int wj = win[t];
        if ((wj >> 4) == tid) sel |= 1u << (wj & 15);
    }
    fl |= sel;
    float v10 = v10s;
    unsigned flp = __shfl_xor(fl, 1);
    if (!(tid & 1))
        maskT[(size_t)(tid >> 1) * N + row] = (fl & 0xffffu) | (flp << 16);
    bool amb = false;
#pragma unroll
    for (int c = 0; c < 16; ++c) {
        if ((sel >> c) & 1) continue;
        float vc = v[c];
        if (vc > v10 - GAPWIN || fabsf(vc - COS_THR) < GAPWIN) amb = true;
    }
    unsigned long long ab = __ballot(amb);
    if (lane == 0) wamb[wid] = (ab != 0ull) ? 1 : 0;
    int cnt = __popc(fl);
    int scan = cnt;
#pragma unroll
    for (int off = 1; off < 64; off <<= 1) {
        int nv = __shfl_up(scan, off);
        if (lane >= off) scan += nv;
    }
    if (lane == 63) wtot[wid] = scan;
    __syncthreads();
    int base = scan - cnt;
    for (int w = 0; w < wid; ++w) base += wtot[w];
    unsigned m = fl;
    int pos = base;
    while (m) {
        int c = __builtin_ctz(m); m &= m - 1;
        int j = tid * 16 + c;
        if (pos < CAP) {
            size_t ofs = (size_t)row * N + j;
            rlist[(size_t)row * CAP + pos] = j;
            rval[(size_t)row * CAP + pos] = w2[ofs] * Hmat[ofs];
        }
        ++pos;
    }
    if (tid == 0) {
        int tot = wtot[0] + wtot[1] + wtot[2] + wtot[3];
        rcnt[row] = tot < CAP ? tot : CAP;
        flagrow[row] = wamb[0] | wamb[1] | wamb[2] | wamb[3];
        v10row[row] = v10;
    }
}

// ---------- exact recompute for ambiguous rows (validated chain) ----------
__global__ __launch_bounds__(256) void fix_rows_k(const int* __restrict__ flagrow,
                                                  const float* __restrict__ v10row,
                                                  const float* __restrict__ x,
                                                  const float* __restrict__ norminv,
                                                  const float* __restrict__ cosm,
                                                  const float* __restrict__ w2,
                                                  const float* __restrict__ Hmat,
                                                  unsigned* __restrict__ maskT,
                                                  int* __restrict__ rlist,
                                                  float* __restrict__ rval,
                                                  int* __restrict__ rcnt) {
    int row = blockIdx.x;
    if (!flagrow[row]) return;
    int tid = threadIdx.x;
    int lane = tid & 63, wid = tid >> 6;
    __shared__ unsigned char flg[N];
    __shared__ unsigned char cnd[N];
    __shared__ int cj[CAP_C];
    __shared__ float exv[CAP_C];
    __shared__ unsigned char sel[CAP_C];
    __shared__ int wcnt[4];
    __shared__ int basev;
    const float* crow = cosm + (size_t)row * N;
    float v[16];
#pragma unroll
    for (int q = 0; q < 4; ++q) {
        float4 f4 = *(const float4*)&crow[tid * 16 + q * 4];
        v[q * 4 + 0] = f4.x; v[q * 4 + 1] = f4.y;
        v[q * 4 + 2] = f4.z; v[q * 4 + 3] = f4.w;
    }
    float v10 = v10row[row];
#pragma unroll
    for (int c = 0; c < 16; ++c) {
        flg[tid * 16 + c] = (v[c] > COS_THR) ? 1 : 0;
        cnd[tid * 16 + c] = (v[c] > v10 - GAPWIN || fabsf(v[c] - COS_THR) < GAPWIN) ? 1 : 0;
    }
    if (tid == 0) basev = 0;
    __syncthreads();
    for (int c = 0; c < 16; ++c) {
        int j = c * 256 + tid;
        bool f = cnd[j] != 0;
        unsigned long long b = __ballot(f);
        if (lane == 0) wcnt[wid] = __popcll(b);
        __syncthreads();
        int off = basev;
        for (int w = 0; w < wid; ++w) off += wcnt[w];
        int pos = off + __popcll(b & ((1ull << lane) - 1ull));
        if (f && pos < CAP_C) cj[pos] = j;
        __syncthreads();
        if (tid == 0) basev += wcnt[0] + wcnt[1] + wcnt[2] + wcnt[3];
        __syncthreads();
    }
    int M = basev < CAP_C ? basev : CAP_C;
    if (tid < M) {
        int j = cj[tid];
        float invr = norminv[row], invj = norminv[j];
        const float* xr = x + (size_t)row * IN_FT;
        const float* xj = x + (size_t)j * IN_FT;
        float acc = 0.f;
        for (int k = 0; k < IN_FT; ++k)
            acc = fmaf(xr[k] * invr, xj[k] * invj, acc);
        exv[tid] = acc;
    }
    __syncthreads();
    if (tid < M) {
        float vv = exv[tid]; int j = cj[tid];
        int rank = 0;
        for (int m = 0; m < M; ++m) {
            float v2 = exv[m]; int j2 = cj[m];
            if (v2 > vv || (v2 == vv && j2 < j)) ++rank;
        }
        sel[tid] = (rank < COS_K) ? 1 : 0;
    }
    __syncthreads();
    if (tid < M) flg[cj[tid]] = ((exv[tid] > COS_THR) || sel[tid]) ? 1 : 0;
    __syncthreads();
    for (int wdx = tid; wdx < NW; wdx += 256) {
        unsigned bits = 0;
#pragma unroll
        for (int b = 0; b < 32; ++b) bits |= (flg[wdx * 32 + b] ? 1u : 0u) << b;
        maskT[(size_t)wdx * N + row] = bits;
    }
    if (tid == 0) basev = 0;
    __syncthreads();
    for (int c = 0; c < 16; ++c) {
        int j = c * 256 + tid;
        bool f = flg[j] != 0;
        unsigned long long b = __ballot(f);
        if (lane == 0) wcnt[wid] = __popcll(b);
        __syncthreads();
        int off = basev;
        for (int w = 0; w < wid; ++w) off += wcnt[w];
        int pos = off + __popcll(b & ((1ull << lane) - 1ull));
        if (f && pos < CAP) {
            size_t ofs = (size_t)row * N + j;
            rlist[(size_t)row * CAP + pos] = j;
            rval[(size_t)row * CAP + pos] = w2[ofs] * Hmat[ofs];
        }
        __syncthreads();
        if (tid == 0) basev += wcnt[0] + wcnt[1] + wcnt[2] + wcnt[3];
        __syncthreads();
    }
    if (tid == 0) rcnt[row] = basev < CAP ? basev : CAP;
}

// ---------- split x and proj_w into bf16 (hi, lo) pairs ----------
__global__ __launch_bounds__(256) void cast_split_k(const float* __restrict__ x,
                                                    const float* __restrict__ w,
                                                    unsigned short* __restrict__ xh,
                                                    unsigned short* __restrict__ xl,
                                                    unsigned short* __restrict__ wh,
                                                    unsigned short* __restrict__ wl) {
    const int totx = (N * IN_FT) / 4;
    int idx = blockIdx.x * 256 + threadIdx.x;
    bool isx = idx < totx;
    int i4 = isx ? idx : idx - totx;
    float4 f = isx ? ((const float4*)x)[i4] : ((const float4*)w)[i4];
    ushort4 hi, lo;
    hi.x = f2bf(f.x); lo.x = f2bf(f.x - bf2f(hi.x));
    hi.y = f2bf(f.y); lo.y = f2bf(f.y - bf2f(hi.y));
    hi.z = f2bf(f.z); lo.z = f2bf(f.z - bf2f(hi.z));
    hi.w = f2bf(f.w); lo.w = f2bf(f.w - bf2f(hi.w));
    if (isx) { ((ushort4*)xh)[i4] = hi; ((ushort4*)xl)[i4] = lo; }
    else     { ((ushort4*)wh)[i4] = hi; ((ushort4*)wl)[i4] = lo; }
}

// ---------- h = x @ proj_w^T + b via bf16x3 MFMA ----------
__global__ __launch_bounds__(256) void proj_mfma_k(const unsigned short* __restrict__ xh,
                                                   const unsigned short* __restrict__ xl,
                                                   const unsigned short* __restrict__ wh,
                                                   const unsigned short* __restrict__ wl,
                                                   const float* __restrict__ bias,
                                                   float* __restrict__ h) {
    int tid = threadIdx.x;
    int wave = tid >> 6, l = tid & 63;
    int m0 = blockIdx.y * 64 + wave * 16;
    int n0 = blockIdx.x * 64;
    int lr = l & 15;
    int kq = (l >> 4) * 8;
    const unsigned short* pah = xh + (size_t)(m0 + lr) * IN_FT + kq;
    const unsigned short* pal = xl + (size_t)(m0 + lr) * IN_FT + kq;
    f32x4 acc[4] = {};
    for (int k0 = 0; k0 < IN_FT; k0 += 32) {
        s16x8 ah = *(const s16x8*)(pah + k0);
        s16x8 al = *(const s16x8*)(pal + k0);
#pragma unroll
        for (int g = 0; g < 4; ++g) {
            const unsigned short* pbh = wh + (size_t)(n0 + g * 16 + lr) * IN_FT + kq + k0;
            const unsigned short* pbl = wl + (size_t)(n0 + g * 16 + lr) * IN_FT + kq + k0;
            s16x8 bh = *(const s16x8*)pbh;
            s16x8 bl = *(const s16x8*)pbl;
            acc[g] = __builtin_amdgcn_mfma_f32_16x16x32_bf16(ah, bh, acc[g], 0, 0, 0);
            acc[g] = __builtin_amdgcn_mfma_f32_16x16x32_bf16(ah, bl, acc[g], 0, 0, 0);
            acc[g] = __builtin_amdgcn_mfma_f32_16x16x32_bf16(al, bh, acc[g], 0, 0, 0);
        }
    }
#pragma unroll
    for (int g = 0; g < 4; ++g)
#pragma unroll
        for (int r = 0; r < 4; ++r) {
            int m = m0 + (l >> 4) * 4 + r;
            int n = n0 + g * 16 + lr;
            h[(size_t)m * OUT_FT + n] = acc[g][r] + bias[n];
        }
}

// ---------- column build pass 1: per-(v-chunk, e) bit counts ----------
__global__ __launch_bounds__(256) void count_cols_k(const unsigned* __restrict__ maskT,
                                                    int* __restrict__ cnt16) {
    __shared__ unsigned ch[8][256];
    int tid = threadIdx.x;
    int eb = blockIdx.x, chunk = blockIdx.y;
    int wbase = eb * 8, v0 = chunk * 256;
#pragma unroll
    for (int i = 0; i < 8; ++i)
        ch[i][tid] = maskT[(size_t)(wbase + i) * N + v0 + tid];
    __syncthreads();
    int wl = tid >> 5, bp = tid & 31;
    int cnt = 0;
#pragma unroll 8
    for (int v = 0; v < 256; ++v) cnt += (ch[wl][v] >> bp) & 1;
    cnt16[chunk * N + eb * 256 + tid] = cnt;
}

// ---------- column build pass 2: fill at prefix offsets (deterministic) ----------
__global__ __launch_bounds__(256) void fill_cols_k(const unsigned* __restrict__ maskT,
                                                   const int* __restrict__ cnt16,
                                                   const float* __restrict__ w1,
                                                   const float* __restrict__ Hmat,
                                                   int* __restrict__ elist,
                                                   float* __restrict__ eval_,
                                                   int* __restrict__ ecnt) {
    __shared__ unsigned ch[8][256];
    int tid = threadIdx.x;
    int eb = blockIdx.x, chunk = blockIdx.y;
    int e = eb * 256 + tid;
    int wbase = eb * 8, v0 = chunk * 256;
#pragma unroll
    for (int i = 0; i < 8; ++i)
        ch[i][tid] = maskT[(size_t)(wbase + i) * N + v0 + tid];
    int pos = 0;
    for (int c = 0; c < chunk; ++c) pos += cnt16[c * N + e];
    __syncthreads();
    int wl = tid >> 5;
    unsigned bit = 1u << (tid & 31);
    for (int v = 0; v < 256; ++v) {
        if (ch[wl][v] & bit) {
            if (pos < CAP) {
                size_t ofs = (size_t)(v0 + v) * N + e;
                elist[(size_t)e * CAP + pos] = v0 + v;
                eval_[(size_t)e * CAP + pos] = w1[ofs] * Hmat[ofs];
            }
            ++pos;
        }
    }
    if (chunk == 15) ecnt[e] = pos < CAP ? pos : CAP;
}

// ---------- dst[i,:] = (1/max(sum|val|,eps)) * sum val*src[list,:] ----------
__global__ __launch_bounds__(256) void spmm_k(const int* __restrict__ list,
                                              const float* __restrict__ val,
                                              const int* __restrict__ cnt,
                                              const float* __restrict__ src,
                                              float* __restrict__ dst) {
    int i = blockIdx.x;
    int f2 = threadIdx.x;
    int c = cnt[i];
    float ssum = 0.f;
    for (int t = 0; t < c; ++t) ssum += fabsf(val[(size_t)i * CAP + t]);
    float acc0 = 0.f, acc1 = 0.f;
    for (int t = 0; t < c; ++t) {
        int j = list[(size_t)i * CAP + t];
        float a = val[(size_t)i * CAP + t];
        float2 s = *(const float2*)&src[(size_t)j * OUT_FT + f2 * 2];
        acc0 += a * s.x;
        acc1 += a * s.y;
    }
    float sc = 1.0f / fmaxf(ssum, EPSN);
    float2 o = make_float2(acc0 * sc, acc1 * sc);
    *(float2*)&dst[(size_t)i * OUT_FT + f2 * 2] = o;
}

extern "C" void kernel_launch(void* const* d_in, const int* in_sizes, int n_in,
                              void* d_out, int out_size, void* d_ws, size_t ws_size,
                              hipStream_t stream) {
    const float* x      = (const float*)d_in[0];   // [4096,512]
    const float* Hmat   = (const float*)d_in[1];   // [4096,4096]
    const float* proj_w = (const float*)d_in[2];   // [512,512]
    const float* proj_b = (const float*)d_in[3];   // [512]
    const float* w1     = (const float*)d_in[4];   // [4096,4096]
    const float* w2     = (const float*)d_in[5];   // [4096,4096]
    float* out = (float*)d_out;

    char* ws = (char*)d_ws;
    unsigned short* xnh   = (unsigned short*)(ws + 0);         // 4 MB
    unsigned short* xnl   = (unsigned short*)(ws + 4194304);   // 4 MB
    float*          cosm  = (float*)(ws + 8388608);            // 64 MB, dead after fix_rows
    int*            elist = (int*)  (ws + 8388608);            // 4 MB (aliases dead cos)
    float*          eval_ = (float*)(ws + 12582912);           // 4 MB (aliases dead cos)
    float*          h     = (float*)(ws + 25165824);           // 8 MB (aliases dead cos)
    float*          h2    = (float*)(ws + 33554432);           // 8 MB (aliases dead cos)
    unsigned short* xhi   = (unsigned short*)(ws + 41943040);  // 4 MB (aliases dead cos)
    unsigned short* xlo   = (unsigned short*)(ws + 46137344);  // 4 MB (aliases dead cos)
    unsigned short* whi   = (unsigned short*)(ws + 50331648);  // 512 KB (aliases dead cos)
    unsigned short* wlo   = (unsigned short*)(ws + 50855936);  // 512 KB (aliases dead cos)
    unsigned*       maskT = (unsigned*)(ws + 75497472);        // 2 MB
    int*            ecnt    = (int*)(ws + 77594624);           // 16 KB
    int*            rcnt    = (int*)(ws + 77611008);           // 16 KB
    float*          norminv = (float*)(ws + 77627392);         // 16 KB
    int*            flagrow = (int*)(ws + 77643776);           // 16 KB
    float*          v10row  = (float*)(ws + 77660160);         // 16 KB
    int*            rlist   = (int*)(ws + 77676544);           // 4 MB
    float*          rval    = (float*)(ws + 81870848);         // 4 MB
    int*            cnt16   = (int*)(ws + 86065152);           // 256 KB

    // 1. norms + bf16 hi/lo of xn
    rownorm_k<<<N, 256, 0, stream>>>(x, xnh, xnl, norminv);
    // 2. approx cos: upper-tri MFMA blocks + fused mirror, swizzled LDS
    cos_gemm_k<<<CNB * (CNB + 1) / 2, 256, 0, stream>>>(xnh, xnl, cosm);
    // 3. top-k + threshold on approx; flag ambiguous rows
    topk_mask_k<<<N, 256, 0, stream>>>(cosm, maskT, w2, Hmat, rlist, rval, rcnt,
                                       flagrow, v10row);
    // 4. exact recompute for flagged rows (reads cosm: before proj aliases it)
    fix_rows_k<<<N, 256, 0, stream>>>(flagrow, v10row, x, norminv, cosm,
                                      w2, Hmat, maskT, rlist, rval, rcnt);
    // 5. h = x @ proj_w^T + proj_b (cos region now dead; h aliases it)
    cast_split_k<<<(N * IN_FT + OUT_FT * IN_FT) / 1024, 256, 0, stream>>>(
        x, proj_w, xhi, xlo, whi, wlo);
    proj_mfma_k<<<dim3(OUT_FT / 64, N / 64), 256, 0, stream>>>(xhi, xlo, whi, wlo, proj_b, h);
    // 6. column lists: count -> fill at prefix offsets
    count_cols_k<<<dim3(16, 16), 256, 0, stream>>>(maskT, cnt16);
    fill_cols_k<<<dim3(16, 16), 256, 0, stream>>>(maskT, cnt16, w1, Hmat, elist, eval_, ecnt);
    // 7. h2[e,:] = normalize . gather-sum over column lists
    spmm_k<<<N, 256, 0, stream>>>(elist, eval_, ecnt, h, h2);
    // 8. out[v,:] = normalize . gather-sum over row lists
    spmm_k<<<N, 256, 0, stream>>>(rlist, rval, rcnt, h2, out);
}

// Round 15
// 279.225 us; speedup vs baseline: 1.7084x; 1.0613x over previous
//
#include <hip/hip_runtime.h>
#include <hip/hip_bf16.h>
#include <math.h>

#define N 4096
#define IN_FT 512
#define OUT_FT 512
#define COS_THR 0.5f
#define COS_K 10
#define EPSN 1e-12f
#define CAP 256          // max stored nnz per row/col (actual ~10)
#define NW (N / 32)      // bitmask words per row
#define CAP_C 128        // candidate slots per flagged row
#define GAPWIN 2e-4f     // ambiguity window; bf16x3 error ~1.5e-5 + mirror ulp
#define CNB 32           // 128-blocks per side

typedef short s16x8 __attribute__((ext_vector_type(8)));
typedef float f32x4 __attribute__((ext_vector_type(4)));

__device__ __forceinline__ unsigned short f2bf(float f) {
    unsigned u = __float_as_uint(f);
    u += 0x7fff + ((u >> 16) & 1);          // RNE to bf16
    return (unsigned short)(u >> 16);
}
__device__ __forceinline__ float bf2f(unsigned short h) {
    return __uint_as_float(((unsigned)h) << 16);
}
__device__ __forceinline__ void gload_lds16(const void* g, void* l) {
    __builtin_amdgcn_global_load_lds(
        (const __attribute__((address_space(1))) void*)g,
        (__attribute__((address_space(3))) void*)l, 16, 0, 0);
}

// ---------- row-normalize: bf16 hi/lo of xn + 1/||x|| + ||x|| ----------
__global__ __launch_bounds__(256) void rownorm_k(const float* __restrict__ x,
                                                 unsigned short* __restrict__ xnh,
                                                 unsigned short* __restrict__ xnl,
                                                 float* __restrict__ norminv,
                                                 float* __restrict__ nrm) {
    int row = blockIdx.x;
    const float* xr = x + (size_t)row * IN_FT;
    float s = 0.f;
    for (int j = threadIdx.x; j < IN_FT; j += 256) { float v = xr[j]; s += v * v; }
    __shared__ float red[256];
    red[threadIdx.x] = s; __syncthreads();
    for (int off = 128; off > 0; off >>= 1) {
        if (threadIdx.x < off) red[threadIdx.x] += red[threadIdx.x + off];
        __syncthreads();
    }
    float nr = fmaxf(sqrtf(red[0]), 1e-12f);
    float inv = 1.0f / nr;
    if (threadIdx.x == 0) { norminv[row] = inv; nrm[row] = nr; }
    for (int j = threadIdx.x; j < IN_FT; j += 256) {
        float v = xr[j] * inv;                 // same op the fix path replays
        unsigned short hi = f2bf(v);
        unsigned short lo = f2bf(v - bf2f(hi));
        xnh[(size_t)row * IN_FT + j] = hi;
        xnl[(size_t)row * IN_FT + j] = lo;
    }
}

// ---------- approx cos: bf16x3 MFMA, upper-tri + fused mirror ----------
// LDS chunk-XOR s(row)=(row>>1)&3 (rule #21: linear gload_lds dest, inverse-
// swizzled global SOURCE, swizzled read): within each 16-lane DS phase the
// rows cover all 4 chunk slots per 128B bank period -> 2-way = free (m136).
// XCD-swizzled block id (528%8==0, bijective): same-by blocks share A panel.
__global__ __launch_bounds__(256) void cos_gemm_k(const unsigned short* __restrict__ xh,
                                                  const unsigned short* __restrict__ xl,
                                                  float* __restrict__ C) {
    __shared__ __align__(16) unsigned short As[2][128 * 32];
    __shared__ __align__(16) unsigned short Bs[2][128 * 32];
    int bid = blockIdx.x;                      // 0 .. 527
    int t = (bid & 7) * 66 + (bid >> 3);       // XCD-chunked bijection
    int by = 0;
    while (t >= CNB - by) { t -= CNB - by; ++by; }
    int bx = by + t;                           // by <= bx
    int tid = threadIdx.x;
    int wave = tid >> 6, l = tid & 63;
    int bi = by * 128, bj = bx * 128;
    int wm = wave >> 1, wn = wave & 1;
    int lm0 = wm * 64, ln0 = wn * 64;
    int lr4 = l >> 2;                          // staging dest row in 16-group
    int lc4s = (((l & 3) ^ ((l >> 3) & 3)) * 8);   // swizzled SOURCE chunk
    int lr = l & 15, lg = l >> 4;
    int kqs = (((l >> 4) ^ ((l >> 1) & 3)) * 8);   // swizzled read chunk
    f32x4 acc[4][4] = {};
    int buf = 0;
#pragma unroll
    for (int q = 0; q < 2; ++q) {
        int r0 = (wave + q * 4) * 16;
        gload_lds16(xh + (size_t)(bi + r0 + lr4) * IN_FT + lc4s, &As[0][r0 * 32]);
        gload_lds16(xh + (size_t)(bj + r0 + lr4) * IN_FT + lc4s, &Bs[0][r0 * 32]);
    }
    asm volatile("s_waitcnt vmcnt(0)" ::: "memory");
    __syncthreads();
    for (int kt = 0; kt < 48; ++kt) {
        if (kt + 1 < 48) {
            int p = (kt + 1) >> 4;
            int kc = ((kt + 1) & 15) * 32;
            const unsigned short* sa = (p == 2) ? xl : xh;
            const unsigned short* sb = (p == 1) ? xl : xh;
#pragma unroll
            for (int q = 0; q < 2; ++q) {
                int r0 = (wave + q * 4) * 16;
                gload_lds16(sa + (size_t)(bi + r0 + lr4) * IN_FT + kc + lc4s,
                            &As[buf ^ 1][r0 * 32]);
                gload_lds16(sb + (size_t)(bj + r0 + lr4) * IN_FT + kc + lc4s,
                            &Bs[buf ^ 1][r0 * 32]);
            }
        }
        s16x8 a[4], b[4];
#pragma unroll
        for (int mi = 0; mi < 4; ++mi)
            a[mi] = *(const s16x8*)&As[buf][(lm0 + mi * 16 + lr) * 32 + kqs];
#pragma unroll
        for (int ni = 0; ni < 4; ++ni)
            b[ni] = *(const s16x8*)&Bs[buf][(ln0 + ni * 16 + lr) * 32 + kqs];
#pragma unroll
        for (int mi = 0; mi < 4; ++mi)
#pragma unroll
            for (int ni = 0; ni < 4; ++ni)
                acc[mi][ni] = __builtin_amdgcn_mfma_f32_16x16x32_bf16(a[mi], b[ni], acc[mi][ni], 0, 0, 0);
        asm volatile("s_waitcnt vmcnt(0)" ::: "memory");
        __syncthreads();
        buf ^= 1;
    }
#pragma unroll
    for (int mi = 0; mi < 4; ++mi)
#pragma unroll
        for (int r = 0; r < 4; ++r) {
            int m = bi + lm0 + mi * 16 + lg * 4 + r;
#pragma unroll
            for (int ni = 0; ni < 4; ++ni)
                C[(size_t)m * N + bj + ln0 + ni * 16 + lr] = acc[mi][ni][r];
        }
    if (bx != by) {
#pragma unroll
        for (int ni = 0; ni < 4; ++ni) {
            int cc = bj + ln0 + ni * 16 + lr;
#pragma unroll
            for (int mi = 0; mi < 4; ++mi) {
                float4 s = make_float4(acc[mi][ni][0], acc[mi][ni][1],
                                       acc[mi][ni][2], acc[mi][ni][3]);
                *(float4*)&C[(size_t)cc * N + bi + lm0 + mi * 16 + lg * 4] = s;
            }
        }
    }
}

// ---------- fused top-k + threshold + inline exact fix for ambiguous rows ----------
// Fast path identical to r14 topk (wave-local top-10 + merge, same total order).
// Ambiguous blocks (block-uniform branch) compact candidates (same set/order
// as r14 fix_rows), exact-recompute with the identical serial fmaf chain,
// re-rank with the identical comparator, correct fl, then write once.
__global__ __launch_bounds__(256) void topk_fix_k(const float* __restrict__ cosm,
                                                  const float* __restrict__ x,
                                                  const float* __restrict__ norminv,
                                                  unsigned* __restrict__ maskT,
                                                  const float* __restrict__ w2,
                                                  const float* __restrict__ Hmat,
                                                  int* __restrict__ rlist,
                                                  float* __restrict__ rval,
                                                  int* __restrict__ rcnt) {
    int row = blockIdx.x;
    int tid = threadIdx.x;
    int lane = tid & 63, wid = tid >> 6;
    __shared__ float wv[4][10];
    __shared__ int   wi[4][10];
    __shared__ int   win[10];
    __shared__ float v10s;
    __shared__ int   wtot[4];
    __shared__ int   wamb[4];
    __shared__ int   cj[CAP_C];
    __shared__ float exv[CAP_C];
    __shared__ unsigned char sel2[CAP_C];
    const float* crow = cosm + (size_t)row * N;
    float v[16];
    unsigned fl = 0;
#pragma unroll
    for (int q = 0; q < 4; ++q) {
        float4 f4 = *(const float4*)&crow[tid * 16 + q * 4];
        v[q * 4 + 0] = f4.x; v[q * 4 + 1] = f4.y;
        v[q * 4 + 2] = f4.z; v[q * 4 + 3] = f4.w;
    }
#pragma unroll
    for (int c = 0; c < 16; ++c)
        if (v[c] > COS_THR) fl |= 1u << c;
    // wave-local top-10 (shfl only; non-destructive exm)
    unsigned exm = 0;
#pragma unroll
    for (int t = 0; t < COS_K; ++t) {
        float best = -INFINITY; int bidx = 0x7fffffff;
#pragma unroll
        for (int c = 0; c < 16; ++c)
            if (!((exm >> c) & 1) && v[c] > best) { best = v[c]; bidx = tid * 16 + c; }
#pragma unroll
        for (int off = 32; off > 0; off >>= 1) {
            float v2 = __shfl_xor(best, off);
            int   i2 = __shfl_xor(bidx, off);
            if (v2 > best || (v2 == best && i2 < bidx)) { best = v2; bidx = i2; }
        }
        if ((bidx >> 4) == tid) exm |= 1u << (bidx & 15);
        if (lane == t) { wv[wid][t] = best; wi[wid][t] = bidx; }
    }
    __syncthreads();
    if (wid == 0) {
        float mv = -INFINITY; int mi = 0x7fffffff;
        if (lane < 40) { int g = lane / 10, s = lane - g * 10; mv = wv[g][s]; mi = wi[g][s]; }
        for (int t = 0; t < COS_K; ++t) {
            float best = mv; int bidx = mi;
#pragma unroll
            for (int off = 32; off > 0; off >>= 1) {
                float v2 = __shfl_xor(best, off);
                int   i2 = __shfl_xor(bidx, off);
                if (v2 > best || (v2 == best && i2 < bidx)) { best = v2; bidx = i2; }
            }
            if (mi == bidx) mv = -INFINITY;
            if (lane == 0) { win[t] = bidx; if (t == COS_K - 1) v10s = best; }
        }
    }
    __syncthreads();
    unsigned sel = 0;
#pragma unroll
    for (int t = 0; t < COS_K; ++t) {
        int wj = win[t];
        if ((wj >> 4) == tid) sel |= 1u << (wj & 15);
    }
    fl |= sel;
    float v10 = v10s;
    // ambiguity: any non-selected value within window of v10 or threshold
    bool amb = false;
#pragma unroll
    for (int c = 0; c < 16; ++c) {
        if ((sel >> c) & 1) continue;
        float vc = v[c];
        if (vc > v10 - GAPWIN || fabsf(vc - COS_THR) < GAPWIN) amb = true;
    }
    unsigned long long ab = __ballot(amb);
    if (lane == 0) wamb[wid] = (ab != 0ull) ? 1 : 0;
    __syncthreads();
    bool blockamb = (wamb[0] | wamb[1] | wamb[2] | wamb[3]) != 0;
    if (blockamb) {
        // candidate mask (r14 fix_rows cnd: value-based; includes selected)
        unsigned cm = 0;
#pragma unroll
        for (int c = 0; c < 16; ++c)
            if (v[c] > v10 - GAPWIN || fabsf(v[c] - COS_THR) < GAPWIN) cm |= 1u << c;
        int ccnt = __popc(cm);
        int cscan = ccnt;
#pragma unroll
        for (int off = 1; off < 64; off <<= 1) {
            int nv = __shfl_up(cscan, off);
            if (lane >= off) cscan += nv;
        }
        if (lane == 63) wtot[wid] = cscan;
        __syncthreads();
        int cbase = cscan - ccnt;
        for (int w = 0; w < wid; ++w) cbase += wtot[w];
        {   // store candidates (ascending j; thread-contiguous ownership)
            unsigned m = cm; int pos = cbase;
            while (m) {
                int c = __builtin_ctz(m); m &= m - 1;
                if (pos < CAP_C) cj[pos] = tid * 16 + c;
                ++pos;
            }
        }
        __syncthreads();
        int Mtot = wtot[0] + wtot[1] + wtot[2] + wtot[3];
        int M = Mtot < CAP_C ? Mtot : CAP_C;
        if (tid < M) {      // exact dots: identical serial ascending-k chain
            int j = cj[tid];
            float invr = norminv[row], invj = norminv[j];
            const float* xr = x + (size_t)row * IN_FT;
            const float* xj = x + (size_t)j * IN_FT;
            float acc = 0.f;
            for (int k = 0; k < IN_FT; ++k)
                acc = fmaf(xr[k] * invr, xj[k] * invj, acc);
            exv[tid] = acc;
        }
        __syncthreads();
        if (tid < M) {      // rank with identical comparator
            float vv = exv[tid]; int j = cj[tid];
            int rank = 0;
            for (int m2 = 0; m2 < M; ++m2) {
                float v2 = exv[m2]; int j2 = cj[m2];
                if (v2 > vv || (v2 == vv && j2 < j)) ++rank;
            }
            sel2[tid] = (rank < COS_K) ? 1 : 0;
        }
        __syncthreads();
        // correct this thread's flags from exact results
        unsigned newfl = 0;
        {
            unsigned m = cm; int pos = cbase;
            unsigned done = 0;
            while (m) {
                int c = __builtin_ctz(m); m &= m - 1;
                bool f;
                if (pos < CAP_C) f = (exv[pos] > COS_THR) || sel2[pos];
                else             f = (v[c] > COS_THR);     // overflow: same as r14
                if (f) newfl |= 1u << c;
                done |= 1u << c;
                ++pos;
            }
#pragma unroll
            for (int c = 0; c < 16; ++c)
                if (!((done >> c) & 1) && v[c] > COS_THR) newfl |= 1u << c;
        }
        fl = newfl;
        __syncthreads();    // wtot reused below
    }
    // transposed bitmask (thread owns 16 contiguous flags = half a word)
    unsigned flp = __shfl_xor(fl, 1);
    if (!(tid & 1))
        maskT[(size_t)(tid >> 1) * N + row] = (fl & 0xffffu) | (flp << 16);
    // row list: popcount + wave scan (ascending j)
    int cnt = __popc(fl);
    int scan = cnt;
#pragma unroll
    for (int off = 1; off < 64; off <<= 1) {
        int nv = __shfl_up(scan, off);
        if (lane >= off) scan += nv;
    }
    if (lane == 63) wtot[wid] = scan;
    __syncthreads();
    int base = scan - cnt;
    for (int w = 0; w < wid; ++w) base += wtot[w];
    unsigned m = fl;
    int pos = base;
    while (m) {
        int c = __builtin_ctz(m); m &= m - 1;
        int j = tid * 16 + c;
        if (pos < CAP) {
            size_t ofs = (size_t)row * N + j;
            rlist[(size_t)row * CAP + pos] = j;
            rval[(size_t)row * CAP + pos] = w2[ofs] * Hmat[ofs];
        }
        ++pos;
    }
    if (tid == 0) {
        int tot = wtot[0] + wtot[1] + wtot[2] + wtot[3];
        rcnt[row] = tot < CAP ? tot : CAP;
    }
}

// ---------- split proj_w into bf16 (hi, lo) ----------
__global__ __launch_bounds__(256) void cast_w_k(const float* __restrict__ w,
                                                unsigned short* __restrict__ wh,
                                                unsigned short* __restrict__ wl) {
    int i4 = blockIdx.x * 256 + threadIdx.x;   // 65536 float4s
    float4 f = ((const float4*)w)[i4];
    ushort4 hi, lo;
    hi.x = f2bf(f.x); lo.x = f2bf(f.x - bf2f(hi.x));
    hi.y = f2bf(f.y); lo.y = f2bf(f.y - bf2f(hi.y));
    hi.z = f2bf(f.z); lo.z = f2bf(f.z - bf2f(hi.z));
    hi.w = f2bf(f.w); lo.w = f2bf(f.w - bf2f(hi.w));
    ((ushort4*)wh)[i4] = hi;
    ((ushort4*)wl)[i4] = lo;
}

// ---------- h = nrm * (xn @ proj_w^T) + b via bf16x3 MFMA ----------
__global__ __launch_bounds__(256) void proj_mfma_k(const unsigned short* __restrict__ xh,
                                                   const unsigned short* __restrict__ xl,
                                                   const unsigned short* __restrict__ wh,
                                                   const unsigned short* __restrict__ wl,
                                                   const float* __restrict__ bias,
                                                   const float* __restrict__ nrm,
                                                   float* __restrict__ h) {
    int tid = threadIdx.x;
    int wave = tid >> 6, l = tid & 63;
    int m0 = blockIdx.y * 64 + wave * 16;
    int n0 = blockIdx.x * 64;
    int lr = l & 15;
    int kq = (l >> 4) * 8;
    const unsigned short* pah = xh + (size_t)(m0 + lr) * IN_FT + kq;
    const unsigned short* pal = xl + (size_t)(m0 + lr) * IN_FT + kq;
    f32x4 acc[4] = {};
    for (int k0 = 0; k0 < IN_FT; k0 += 32) {
        s16x8 ah = *(const s16x8*)(pah + k0);
        s16x8 al = *(const s16x8*)(pal + k0);
#pragma unroll
        for (int g = 0; g < 4; ++g) {
            const unsigned short* pbh = wh + (size_t)(n0 + g * 16 + lr) * IN_FT + kq + k0;
            const unsigned short* pbl = wl + (size_t)(n0 + g * 16 + lr) * IN_FT + kq + k0;
            s16x8 bh = *(const s16x8*)pbh;
            s16x8 bl = *(const s16x8*)pbl;
            acc[g] = __builtin_amdgcn_mfma_f32_16x16x32_bf16(ah, bh, acc[g], 0, 0, 0);
            acc[g] = __builtin_amdgcn_mfma_f32_16x16x32_bf16(ah, bl, acc[g], 0, 0, 0);
            acc[g] = __builtin_amdgcn_mfma_f32_16x16x32_bf16(al, bh, acc[g], 0, 0, 0);
        }
    }
#pragma unroll
    for (int g = 0; g < 4; ++g)
#pragma unroll
        for (int r = 0; r < 4; ++r) {
            int m = m0 + (l >> 4) * 4 + r;
            int n = n0 + g * 16 + lr;
            h[(size_t)m * OUT_FT + n] = nrm[m] * acc[g][r] + bias[n];
        }
}

// ---------- column build pass 1: per-(v-chunk, e) bit counts ----------
__global__ __launch_bounds__(256) void count_cols_k(const unsigned* __restrict__ maskT,
                                                    int* __restrict__ cnt16) {
    __shared__ unsigned ch[8][256];
    int tid = threadIdx.x;
    int eb = blockIdx.x, chunk = blockIdx.y;
    int wbase = eb * 8, v0 = chunk * 256;
#pragma unroll
    for (int i = 0; i < 8; ++i)
        ch[i][tid] = maskT[(size_t)(wbase + i) * N + v0 + tid];
    __syncthreads();
    int wl = tid >> 5, bp = tid & 31;
    int cnt = 0;
#pragma unroll 8
    for (int v = 0; v < 256; ++v) cnt += (ch[wl][v] >> bp) & 1;
    cnt16[chunk * N + eb * 256 + tid] = cnt;
}

// ---------- column build pass 2: fill at prefix offsets (deterministic) ----------
__global__ __launch_bounds__(256) void fill_cols_k(const unsigned* __restrict__ maskT,
                                                   const int* __restrict__ cnt16,
                                                   const float* __restrict__ w1,
                                                   const float* __restrict__ Hmat,
                                                   int* __restrict__ elist,
                                                   float* __restrict__ eval_,
                                                   int* __restrict__ ecnt) {
    __shared__ unsigned ch[8][256];
    int tid = threadIdx.x;
    int eb = blockIdx.x, chunk = blockIdx.y;
    int e = eb * 256 + tid;
    int wbase = eb * 8, v0 = chunk * 256;
#pragma unroll
    for (int i = 0; i < 8; ++i)
        ch[i][tid] = maskT[(size_t)(wbase + i) * N + v0 + tid];
    int pos = 0;
    for (int c = 0; c < chunk; ++c) pos += cnt16[c * N + e];
    __syncthreads();
    int wl = tid >> 5;
    unsigned bit = 1u << (tid & 31);
    for (int v = 0; v < 256; ++v) {
        if (ch[wl][v] & bit) {
            if (pos < CAP) {
                size_t ofs = (size_t)(v0 + v) * N + e;
                elist[(size_t)e * CAP + pos] = v0 + v;
                eval_[(size_t)e * CAP + pos] = w1[ofs] * Hmat[ofs];
            }
            ++pos;
        }
    }
    if (chunk == 15) ecnt[e] = pos < CAP ? pos : CAP;
}

// ---------- dst[i,:] = (1/max(sum|val|,eps)) * sum val*src[list,:] ----------
__global__ __launch_bounds__(256) void spmm_k(const int* __restrict__ list,
                                              const float* __restrict__ val,
                                              const int* __restrict__ cnt,
                                              const float* __restrict__ src,
                                              float* __restrict__ dst) {
    int i = blockIdx.x;
    int f2 = threadIdx.x;
    int c = cnt[i];
    float ssum = 0.f;
    for (int t = 0; t < c; ++t) ssum += fabsf(val[(size_t)i * CAP + t]);
    float acc0 = 0.f, acc1 = 0.f;
    for (int t = 0; t < c; ++t) {
        int j = list[(size_t)i * CAP + t];
        float a = val[(size_t)i * CAP + t];
        float2 s = *(const float2*)&src[(size_t)j * OUT_FT + f2 * 2];
        acc0 += a * s.x;
        acc1 += a * s.y;
    }
    float sc = 1.0f / fmaxf(ssum, EPSN);
    float2 o = make_float2(acc0 * sc, acc1 * sc);
    *(float2*)&dst[(size_t)i * OUT_FT + f2 * 2] = o;
}

extern "C" void kernel_launch(void* const* d_in, const int* in_sizes, int n_in,
                              void* d_out, int out_size, void* d_ws, size_t ws_size,
                              hipStream_t stream) {
    const float* x      = (const float*)d_in[0];   // [4096,512]
    const float* Hmat   = (const float*)d_in[1];   // [4096,4096]
    const float* proj_w = (const float*)d_in[2];   // [512,512]
    const float* proj_b = (const float*)d_in[3];   // [512]
    const float* w1     = (const float*)d_in[4];   // [4096,4096]
    const float* w2     = (const float*)d_in[5];   // [4096,4096]
    float* out = (float*)d_out;

    char* ws = (char*)d_ws;
    unsigned short* xnh   = (unsigned short*)(ws + 0);         // 4 MB
    unsigned short* xnl   = (unsigned short*)(ws + 4194304);   // 4 MB
    float*          cosm  = (float*)(ws + 8388608);            // 64 MB, dead after topk_fix
    int*            elist = (int*)  (ws + 8388608);            // 4 MB (aliases dead cos)
    float*          eval_ = (float*)(ws + 12582912);           // 4 MB (aliases dead cos)
    float*          h     = (float*)(ws + 25165824);           // 8 MB (aliases dead cos)
    float*          h2    = (float*)(ws + 33554432);           // 8 MB (aliases dead cos)
    unsigned short* whi   = (unsigned short*)(ws + 50331648);  // 512 KB (aliases dead cos)
    unsigned short* wlo   = (unsigned short*)(ws + 50855936);  // 512 KB (aliases dead cos)
    unsigned*       maskT = (unsigned*)(ws + 75497472);        // 2 MB
    int*            ecnt    = (int*)(ws + 77594624);           // 16 KB
    int*            rcnt    = (int*)(ws + 77611008);           // 16 KB
    float*          norminv = (float*)(ws + 77627392);         // 16 KB
    float*          nrm     = (float*)(ws + 77643776);         // 16 KB
    int*            rlist   = (int*)(ws + 77676544);           // 4 MB
    float*          rval    = (float*)(ws + 81870848);         // 4 MB
    int*            cnt16   = (int*)(ws + 86065152);           // 256 KB

    // 1. norms + bf16 hi/lo of xn
    rownorm_k<<<N, 256, 0, stream>>>(x, xnh, xnl, norminv, nrm);
    // 2. approx cos: upper-tri MFMA + fused mirror, fixed swizzle, XCD blocks
    cos_gemm_k<<<CNB * (CNB + 1) / 2, 256, 0, stream>>>(xnh, xnl, cosm);
    // 3. fused top-k + threshold + inline exact fix -> maskT + row lists
    topk_fix_k<<<N, 256, 0, stream>>>(cosm, x, norminv, maskT, w2, Hmat,
                                      rlist, rval, rcnt);
    // 4. h = nrm*(xn @ proj_w^T) + b (cos region now dead; h aliases it)
    cast_w_k<<<256, 256, 0, stream>>>(proj_w, whi, wlo);
    proj_mfma_k<<<dim3(OUT_FT / 64, N / 64), 256, 0, stream>>>(xnh, xnl, whi, wlo,
                                                               proj_b, nrm, h);
    // 5. column lists: count -> fill at prefix offsets
    count_cols_k<<<dim3(16, 16), 256, 0, stream>>>(maskT, cnt16);
    fill_cols_k<<<dim3(16, 16), 256, 0, stream>>>(maskT, cnt16, w1, Hmat, elist, eval_, ecnt);
    // 6. h2[e,:] = normalize . gather-sum over column lists
    spmm_k<<<N, 256, 0, stream>>>(elist, eval_, ecnt, h, h2);
    // 7. out[v,:] = normalize . gather-sum over row lists
    spmm_k<<<N, 256, 0, stream>>>(rlist, rval, rcnt, h2, out);
}

// Round 16
// 269.387 us; speedup vs baseline: 1.7708x; 1.0365x over previous
//
#include <hip/hip_runtime.h>
#include <hip/hip_bf16.h>
#include <math.h>

#define N 4096
#define IN_FT 512
#define OUT_FT 512
#define COS_THR 0.5f
#define COS_K 10
#define EPSN 1e-12f
#define CAP 256          // max stored nnz per row/col (actual ~10)
#define NW (N / 32)      // bitmask words per row
#define CAP_C 128        // candidate slots per flagged row (fix path)
#define GAPWIN 2e-4f     // ambiguity window; bf16x3 error ~1.5e-5 + mirror ulp
#define CNB 32           // 128-blocks per side
#define T0 0.08f         // top-k prefilter threshold (data-checked, fallback-safe)
#define CAPT 512         // prefilter candidate capacity

typedef short s16x8 __attribute__((ext_vector_type(8)));
typedef float f32x4 __attribute__((ext_vector_type(4)));

__device__ __forceinline__ unsigned short f2bf(float f) {
    unsigned u = __float_as_uint(f);
    u += 0x7fff + ((u >> 16) & 1);          // RNE to bf16
    return (unsigned short)(u >> 16);
}
__device__ __forceinline__ float bf2f(unsigned short h) {
    return __uint_as_float(((unsigned)h) << 16);
}
__device__ __forceinline__ void gload_lds16(const void* g, void* l) {
    __builtin_amdgcn_global_load_lds(
        (const __attribute__((address_space(1))) void*)g,
        (__attribute__((address_space(3))) void*)l, 16, 0, 0);
}

// ---------- row-normalize: bf16 hi/lo of xn + 1/||x|| + ||x|| ----------
__global__ __launch_bounds__(256) void rownorm_k(const float* __restrict__ x,
                                                 unsigned short* __restrict__ xnh,
                                                 unsigned short* __restrict__ xnl,
                                                 float* __restrict__ norminv,
                                                 float* __restrict__ nrm) {
    int row = blockIdx.x;
    const float* xr = x + (size_t)row * IN_FT;
    float s = 0.f;
    for (int j = threadIdx.x; j < IN_FT; j += 256) { float v = xr[j]; s += v * v; }
    __shared__ float red[256];
    red[threadIdx.x] = s; __syncthreads();
    for (int off = 128; off > 0; off >>= 1) {
        if (threadIdx.x < off) red[threadIdx.x] += red[threadIdx.x + off];
        __syncthreads();
    }
    float nr = fmaxf(sqrtf(red[0]), 1e-12f);
    float inv = 1.0f / nr;
    if (threadIdx.x == 0) { norminv[row] = inv; nrm[row] = nr; }
    for (int j = threadIdx.x; j < IN_FT; j += 256) {
        float v = xr[j] * inv;                 // same op the fix path replays
        unsigned short hi = f2bf(v);
        unsigned short lo = f2bf(v - bf2f(hi));
        xnh[(size_t)row * IN_FT + j] = hi;
        xnl[(size_t)row * IN_FT + j] = lo;
    }
}

// ---------- approx cos: bf16x3 MFMA, upper-tri + fused mirror ----------
__global__ __launch_bounds__(256) void cos_gemm_k(const unsigned short* __restrict__ xh,
                                                  const unsigned short* __restrict__ xl,
                                                  float* __restrict__ C) {
    __shared__ __align__(16) unsigned short As[2][128 * 32];
    __shared__ __align__(16) unsigned short Bs[2][128 * 32];
    int bid = blockIdx.x;                      // 0 .. 527
    int t = (bid & 7) * 66 + (bid >> 3);       // XCD-chunked bijection
    int by = 0;
    while (t >= CNB - by) { t -= CNB - by; ++by; }
    int bx = by + t;                           // by <= bx
    int tid = threadIdx.x;
    int wave = tid >> 6, l = tid & 63;
    int bi = by * 128, bj = bx * 128;
    int wm = wave >> 1, wn = wave & 1;
    int lm0 = wm * 64, ln0 = wn * 64;
    int lr4 = l >> 2;
    int lc4s = (((l & 3) ^ ((l >> 3) & 3)) * 8);   // swizzled SOURCE chunk
    int lr = l & 15, lg = l >> 4;
    int kqs = (((l >> 4) ^ ((l >> 1) & 3)) * 8);   // swizzled read chunk
    f32x4 acc[4][4] = {};
    int buf = 0;
#pragma unroll
    for (int q = 0; q < 2; ++q) {
        int r0 = (wave + q * 4) * 16;
        gload_lds16(xh + (size_t)(bi + r0 + lr4) * IN_FT + lc4s, &As[0][r0 * 32]);
        gload_lds16(xh + (size_t)(bj + r0 + lr4) * IN_FT + lc4s, &Bs[0][r0 * 32]);
    }
    asm volatile("s_waitcnt vmcnt(0)" ::: "memory");
    __syncthreads();
    for (int kt = 0; kt < 48; ++kt) {
        if (kt + 1 < 48) {
            int p = (kt + 1) >> 4;
            int kc = ((kt + 1) & 15) * 32;
            const unsigned short* sa = (p == 2) ? xl : xh;
            const unsigned short* sb = (p == 1) ? xl : xh;
#pragma unroll
            for (int q = 0; q < 2; ++q) {
                int r0 = (wave + q * 4) * 16;
                gload_lds16(sa + (size_t)(bi + r0 + lr4) * IN_FT + kc + lc4s,
                            &As[buf ^ 1][r0 * 32]);
                gload_lds16(sb + (size_t)(bj + r0 + lr4) * IN_FT + kc + lc4s,
                            &Bs[buf ^ 1][r0 * 32]);
            }
        }
        s16x8 a[4], b[4];
#pragma unroll
        for (int mi = 0; mi < 4; ++mi)
            a[mi] = *(const s16x8*)&As[buf][(lm0 + mi * 16 + lr) * 32 + kqs];
#pragma unroll
        for (int ni = 0; ni < 4; ++ni)
            b[ni] = *(const s16x8*)&Bs[buf][(ln0 + ni * 16 + lr) * 32 + kqs];
#pragma unroll
        for (int mi = 0; mi < 4; ++mi)
#pragma unroll
            for (int ni = 0; ni < 4; ++ni)
                acc[mi][ni] = __builtin_amdgcn_mfma_f32_16x16x32_bf16(a[mi], b[ni], acc[mi][ni], 0, 0, 0);
        asm volatile("s_waitcnt vmcnt(0)" ::: "memory");
        __syncthreads();
        buf ^= 1;
    }
#pragma unroll
    for (int mi = 0; mi < 4; ++mi)
#pragma unroll
        for (int r = 0; r < 4; ++r) {
            int m = bi + lm0 + mi * 16 + lg * 4 + r;
#pragma unroll
            for (int ni = 0; ni < 4; ++ni)
                C[(size_t)m * N + bj + ln0 + ni * 16 + lr] = acc[mi][ni][r];
        }
    if (bx != by) {
#pragma unroll
        for (int ni = 0; ni < 4; ++ni) {
            int cc = bj + ln0 + ni * 16 + lr;
#pragma unroll
            for (int mi = 0; mi < 4; ++mi) {
                float4 s = make_float4(acc[mi][ni][0], acc[mi][ni][1],
                                       acc[mi][ni][2], acc[mi][ni][3]);
                *(float4*)&C[(size_t)cc * N + bi + lm0 + mi * 16 + lg * 4] = s;
            }
        }
    }
}

// ---------- fused top-k + threshold + inline exact fix ----------
// NEW: prefilter v > T0. If measured count M in [10, CAPT]: top-10(row) ==
// top-10(candidates) PROVABLY (all top-10 values > T0 since v10 >= 10th
// candidate > T0, and every value > T0 is a candidate). Wave 0 extracts with
// the identical (value desc, index asc) comparator -> win sequence + v10
// bit-identical. Else: unchanged r15 full path (block-uniform). Downstream
// (ambiguity window, exact fix, maskT, lists) byte-identical to r15.
__global__ __launch_bounds__(256) void topk_fix_k(const float* __restrict__ cosm,
                                                  const float* __restrict__ x,
                                                  const float* __restrict__ norminv,
                                                  unsigned* __restrict__ maskT,
                                                  const float* __restrict__ w2,
                                                  const float* __restrict__ Hmat,
                                                  int* __restrict__ rlist,
                                                  float* __restrict__ rval,
                                                  int* __restrict__ rcnt) {
    int row = blockIdx.x;
    int tid = threadIdx.x;
    int lane = tid & 63, wid = tid >> 6;
    __shared__ float wv[4][10];
    __shared__ int   wi[4][10];
    __shared__ int   win[10];
    __shared__ float v10s;
    __shared__ int   wtot[4];
    __shared__ int   wtotc[4];
    __shared__ int   wamb[4];
    __shared__ int   cj[CAP_C];
    __shared__ float exv[CAP_C];
    __shared__ unsigned char sel2[CAP_C];
    __shared__ float cv2[CAPT];
    __shared__ int   ci2[CAPT];
    const float* crow = cosm + (size_t)row * N;
    float v[16];
    unsigned fl = 0;
#pragma unroll
    for (int q = 0; q < 4; ++q) {
        float4 f4 = *(const float4*)&crow[tid * 16 + q * 4];
        v[q * 4 + 0] = f4.x; v[q * 4 + 1] = f4.y;
        v[q * 4 + 2] = f4.z; v[q * 4 + 3] = f4.w;
    }
#pragma unroll
    for (int c = 0; c < 16; ++c)
        if (v[c] > COS_THR) fl |= 1u << c;
    // ---- prefilter: candidates v > T0, block compaction (ascending j) ----
    unsigned pm = 0;
#pragma unroll
    for (int c = 0; c < 16; ++c)
        if (v[c] > T0) pm |= 1u << c;
    {
        int pcnt = __popc(pm);
        int pscan = pcnt;
#pragma unroll
        for (int off = 1; off < 64; off <<= 1) {
            int nv = __shfl_up(pscan, off);
            if (lane >= off) pscan += nv;
        }
        if (lane == 63) wtotc[wid] = pscan;
        __syncthreads();
        int pbase = pscan - pcnt;
        for (int w = 0; w < wid; ++w) pbase += wtotc[w];
        unsigned m = pm; int pos = pbase;
        while (m) {
            int c = __builtin_ctz(m); m &= m - 1;
            if (pos < CAPT) { cv2[pos] = v[c]; ci2[pos] = tid * 16 + c; }
            ++pos;
        }
    }
    __syncthreads();
    int Mc = wtotc[0] + wtotc[1] + wtotc[2] + wtotc[3];
    bool fast = (Mc >= COS_K && Mc <= CAPT);
    if (fast) {
        // ---- wave 0: exact top-10 over candidates (identical comparator) ----
        if (wid == 0) {
            float cv[8]; int ci[8];
            int Kc = (Mc + 63) >> 6;
#pragma unroll
            for (int s = 0; s < 8; ++s) {
                int p = s * 64 + lane;
                bool ok = (s < Kc) && (p < Mc);
                cv[s] = ok ? cv2[p] : -INFINITY;
                ci[s] = ok ? ci2[p] : 0x7fffffff;
            }
            unsigned exm = 0;
            for (int t = 0; t < COS_K; ++t) {
                float best = -INFINITY; int bidx = 0x7fffffff;
#pragma unroll
                for (int s = 0; s < 8; ++s)   // ascending s = ascending j
                    if (!((exm >> s) & 1) && cv[s] > best) { best = cv[s]; bidx = ci[s]; }
#pragma unroll
                for (int off = 32; off > 0; off >>= 1) {
                    float v2 = __shfl_xor(best, off);
                    int   i2 = __shfl_xor(bidx, off);
                    if (v2 > best || (v2 == best && i2 < bidx)) { best = v2; bidx = i2; }
                }
#pragma unroll
                for (int s = 0; s < 8; ++s)   // winner idx unique -> owner marks
                    if (ci[s] == bidx) exm |= 1u << s;
                if (lane == 0) { win[t] = bidx; if (t == COS_K - 1) v10s = best; }
            }
        }
        __syncthreads();
    } else {
        // ---- fallback: r15 full path (wave-local top-10 + merge) ----
        unsigned exm = 0;
#pragma unroll
        for (int t = 0; t < COS_K; ++t) {
            float best = -INFINITY; int bidx = 0x7fffffff;
#pragma unroll
            for (int c = 0; c < 16; ++c)
                if (!((exm >> c) & 1) && v[c] > best) { best = v[c]; bidx = tid * 16 + c; }
#pragma unroll
            for (int off = 32; off > 0; off >>= 1) {
                float v2 = __shfl_xor(best, off);
                int   i2 = __shfl_xor(bidx, off);
                if (v2 > best || (v2 == best && i2 < bidx)) { best = v2; bidx = i2; }
            }
            if ((bidx >> 4) == tid) exm |= 1u << (bidx & 15);
            if (lane == t) { wv[wid][t] = best; wi[wid][t] = bidx; }
        }
        __syncthreads();
        if (wid == 0) {
            float mv = -INFINITY; int mi = 0x7fffffff;
            if (lane < 40) { int g = lane / 10, s = lane - g * 10; mv = wv[g][s]; mi = wi[g][s]; }
            for (int t = 0; t < COS_K; ++t) {
                float best = mv; int bidx = mi;
#pragma unroll
                for (int off = 32; off > 0; off >>= 1) {
                    float v2 = __shfl_xor(best, off);
                    int   i2 = __shfl_xor(bidx, off);
                    if (v2 > best || (v2 == best && i2 < bidx)) { best = v2; bidx = i2; }
                }
                if (mi == bidx) mv = -INFINITY;
                if (lane == 0) { win[t] = bidx; if (t == COS_K - 1) v10s = best; }
            }
        }
        __syncthreads();
    }
    unsigned sel = 0;
#pragma unroll
    for (int t = 0; t < COS_K; ++t) {
        int wj = win[t];
        if ((wj >> 4) == tid) sel |= 1u << (wj & 15);
    }
    fl |= sel;
    float v10 = v10s;
    // ambiguity: any non-selected value within window of v10 or threshold
    bool amb = false;
#pragma unroll
    for (int c = 0; c < 16; ++c) {
        if ((sel >> c) & 1) continue;
        float vc = v[c];
        if (vc > v10 - GAPWIN || fabsf(vc - COS_THR) < GAPWIN) amb = true;
    }
    unsigned long long ab = __ballot(amb);
    if (lane == 0) wamb[wid] = (ab != 0ull) ? 1 : 0;
    __syncthreads();
    bool blockamb = (wamb[0] | wamb[1] | wamb[2] | wamb[3]) != 0;
    if (blockamb) {
        unsigned cm = 0;
#pragma unroll
        for (int c = 0; c < 16; ++c)
            if (v[c] > v10 - GAPWIN || fabsf(v[c] - COS_THR) < GAPWIN) cm |= 1u << c;
        int ccnt = __popc(cm);
        int cscan = ccnt;
#pragma unroll
        for (int off = 1; off < 64; off <<= 1) {
            int nv = __shfl_up(cscan, off);
            if (lane >= off) cscan += nv;
        }
        if (lane == 63) wtot[wid] = cscan;
        __syncthreads();
        int cbase = cscan - ccnt;
        for (int w = 0; w < wid; ++w) cbase += wtot[w];
        {
            unsigned m = cm; int pos = cbase;
            while (m) {
                int c = __builtin_ctz(m); m &= m - 1;
                if (pos < CAP_C) cj[pos] = tid * 16 + c;
                ++pos;
            }
        }
        __syncthreads();
        int Mtot = wtot[0] + wtot[1] + wtot[2] + wtot[3];
        int M = Mtot < CAP_C ? Mtot : CAP_C;
        if (tid < M) {      // exact dots: identical serial ascending-k chain
            int j = cj[tid];
            float invr = norminv[row], invj = norminv[j];
            const float* xr = x + (size_t)row * IN_FT;
            const float* xj = x + (size_t)j * IN_FT;
            float acc = 0.f;
            for (int k = 0; k < IN_FT; ++k)
                acc = fmaf(xr[k] * invr, xj[k] * invj, acc);
            exv[tid] = acc;
        }
        __syncthreads();
        if (tid < M) {
            float vv = exv[tid]; int j = cj[tid];
            int rank = 0;
            for (int m2 = 0; m2 < M; ++m2) {
                float v2 = exv[m2]; int j2 = cj[m2];
                if (v2 > vv || (v2 == vv && j2 < j)) ++rank;
            }
            sel2[tid] = (rank < COS_K) ? 1 : 0;
        }
        __syncthreads();
        unsigned newfl = 0;
        {
            unsigned m = cm; int pos = cbase;
            unsigned done = 0;
            while (m) {
                int c = __builtin_ctz(m); m &= m - 1;
                bool f;
                if (pos < CAP_C) f = (exv[pos] > COS_THR) || sel2[pos];
                else             f = (v[c] > COS_THR);
                if (f) newfl |= 1u << c;
                done |= 1u << c;
                ++pos;
            }
#pragma unroll
            for (int c = 0; c < 16; ++c)
                if (!((done >> c) & 1) && v[c] > COS_THR) newfl |= 1u << c;
        }
        fl = newfl;
        __syncthreads();
    }
    unsigned flp = __shfl_xor(fl, 1);
    if (!(tid & 1))
        maskT[(size_t)(tid >> 1) * N + row] = (fl & 0xffffu) | (flp << 16);
    int cnt = __popc(fl);
    int scan = cnt;
#pragma unroll
    for (int off = 1; off < 64; off <<= 1) {
        int nv = __shfl_up(scan, off);
        if (lane >= off) scan += nv;
    }
    if (lane == 63) wtot[wid] = scan;
    __syncthreads();
    int base = scan - cnt;
    for (int w = 0; w < wid; ++w) base += wtot[w];
    unsigned m = fl;
    int pos = base;
    while (m) {
        int c = __builtin_ctz(m); m &= m - 1;
        int j = tid * 16 + c;
        if (pos < CAP) {
            size_t ofs = (size_t)row * N + j;
            rlist[(size_t)row * CAP + pos] = j;
            rval[(size_t)row * CAP + pos] = w2[ofs] * Hmat[ofs];
        }
        ++pos;
    }
    if (tid == 0) {
        int tot = wtot[0] + wtot[1] + wtot[2] + wtot[3];
        rcnt[row] = tot < CAP ? tot : CAP;
    }
}

// ---------- split proj_w into bf16 (hi, lo) ----------
__global__ __launch_bounds__(256) void cast_w_k(const float* __restrict__ w,
                                                unsigned short* __restrict__ wh,
                                                unsigned short* __restrict__ wl) {
    int i4 = blockIdx.x * 256 + threadIdx.x;   // 65536 float4s
    float4 f = ((const float4*)w)[i4];
    ushort4 hi, lo;
    hi.x = f2bf(f.x); lo.x = f2bf(f.x - bf2f(hi.x));
    hi.y = f2bf(f.y); lo.y = f2bf(f.y - bf2f(hi.y));
    hi.z = f2bf(f.z); lo.z = f2bf(f.z - bf2f(hi.z));
    hi.w = f2bf(f.w); lo.w = f2bf(f.w - bf2f(hi.w));
    ((ushort4*)wh)[i4] = hi;
    ((ushort4*)wl)[i4] = lo;
}

// ---------- h = nrm * (xn @ proj_w^T) + b via bf16x3 MFMA ----------
__global__ __launch_bounds__(256) void proj_mfma_k(const unsigned short* __restrict__ xh,
                                                   const unsigned short* __restrict__ xl,
                                                   const unsigned short* __restrict__ wh,
                                                   const unsigned short* __restrict__ wl,
                                                   const float* __restrict__ bias,
                                                   const float* __restrict__ nrm,
                                                   float* __restrict__ h) {
    int tid = threadIdx.x;
    int wave = tid >> 6, l = tid & 63;
    int m0 = blockIdx.y * 64 + wave * 16;
    int n0 = blockIdx.x * 64;
    int lr = l & 15;
    int kq = (l >> 4) * 8;
    const unsigned short* pah = xh + (size_t)(m0 + lr) * IN_FT + kq;
    const unsigned short* pal = xl + (size_t)(m0 + lr) * IN_FT + kq;
    f32x4 acc[4] = {};
    for (int k0 = 0; k0 < IN_FT; k0 += 32) {
        s16x8 ah = *(const s16x8*)(pah + k0);
        s16x8 al = *(const s16x8*)(pal + k0);
#pragma unroll
        for (int g = 0; g < 4; ++g) {
            const unsigned short* pbh = wh + (size_t)(n0 + g * 16 + lr) * IN_FT + kq + k0;
            const unsigned short* pbl = wl + (size_t)(n0 + g * 16 + lr) * IN_FT + kq + k0;
            s16x8 bh = *(const s16x8*)pbh;
            s16x8 bl = *(const s16x8*)pbl;
            acc[g] = __builtin_amdgcn_mfma_f32_16x16x32_bf16(ah, bh, acc[g], 0, 0, 0);
            acc[g] = __builtin_amdgcn_mfma_f32_16x16x32_bf16(ah, bl, acc[g], 0, 0, 0);
            acc[g] = __builtin_amdgcn_mfma_f32_16x16x32_bf16(al, bh, acc[g], 0, 0, 0);
        }
    }
#pragma unroll
    for (int g = 0; g < 4; ++g)
#pragma unroll
        for (int r = 0; r < 4; ++r) {
            int m = m0 + (l >> 4) * 4 + r;
            int n = n0 + g * 16 + lr;
            h[(size_t)m * OUT_FT + n] = nrm[m] * acc[g][r] + bias[n];
        }
}

// ---------- column build pass 1: per-(v-chunk, e) bit counts ----------
__global__ __launch_bounds__(256) void count_cols_k(const unsigned* __restrict__ maskT,
                                                    int* __restrict__ cnt16) {
    __shared__ unsigned ch[8][256];
    int tid = threadIdx.x;
    int eb = blockIdx.x, chunk = blockIdx.y;
    int wbase = eb * 8, v0 = chunk * 256;
#pragma unroll
    for (int i = 0; i < 8; ++i)
        ch[i][tid] = maskT[(size_t)(wbase + i) * N + v0 + tid];
    __syncthreads();
    int wl = tid >> 5, bp = tid & 31;
    int cnt = 0;
#pragma unroll 8
    for (int v = 0; v < 256; ++v) cnt += (ch[wl][v] >> bp) & 1;
    cnt16[chunk * N + eb * 256 + tid] = cnt;
}

// ---------- column build pass 2: fill at prefix offsets (deterministic) ----------
__global__ __launch_bounds__(256) void fill_cols_k(const unsigned* __restrict__ maskT,
                                                   const int* __restrict__ cnt16,
                                                   const float* __restrict__ w1,
                                                   const float* __restrict__ Hmat,
                                                   int* __restrict__ elist,
                                                   float* __restrict__ eval_,
                                                   int* __restrict__ ecnt) {
    __shared__ unsigned ch[8][256];
    int tid = threadIdx.x;
    int eb = blockIdx.x, chunk = blockIdx.y;
    int e = eb * 256 + tid;
    int wbase = eb * 8, v0 = chunk * 256;
#pragma unroll
    for (int i = 0; i < 8; ++i)
        ch[i][tid] = maskT[(size_t)(wbase + i) * N + v0 + tid];
    int pos = 0;
    for (int c = 0; c < chunk; ++c) pos += cnt16[c * N + e];
    __syncthreads();
    int wl = tid >> 5;
    unsigned bit = 1u << (tid & 31);
    for (int v = 0; v < 256; ++v) {
        if (ch[wl][v] & bit) {
            if (pos < CAP) {
                size_t ofs = (size_t)(v0 + v) * N + e;
                elist[(size_t)e * CAP + pos] = v0 + v;
                eval_[(size_t)e * CAP + pos] = w1[ofs] * Hmat[ofs];
            }
            ++pos;
        }
    }
    if (chunk == 15) ecnt[e] = pos < CAP ? pos : CAP;
}

// ---------- dst[i,:] = (1/max(sum|val|,eps)) * sum val*src[list,:] ----------
__global__ __launch_bounds__(256) void spmm_k(const int* __restrict__ list,
                                              const float* __restrict__ val,
                                              const int* __restrict__ cnt,
                                              const float* __restrict__ src,
                                              float* __restrict__ dst) {
    int i = blockIdx.x;
    int f2 = threadIdx.x;
    int c = cnt[i];
    float ssum = 0.f;
    for (int t = 0; t < c; ++t) ssum += fabsf(val[(size_t)i * CAP + t]);
    float acc0 = 0.f, acc1 = 0.f;
    for (int t = 0; t < c; ++t) {
        int j = list[(size_t)i * CAP + t];
        float a = val[(size_t)i * CAP + t];
        float2 s = *(const float2*)&src[(size_t)j * OUT_FT + f2 * 2];
        acc0 += a * s.x;
        acc1 += a * s.y;
    }
    float sc = 1.0f / fmaxf(ssum, EPSN);
    float2 o = make_float2(acc0 * sc, acc1 * sc);
    *(float2*)&dst[(size_t)i * OUT_FT + f2 * 2] = o;
}

extern "C" void kernel_launch(void* const* d_in, const int* in_sizes, int n_in,
                              void* d_out, int out_size, void* d_ws, size_t ws_size,
                              hipStream_t stream) {
    const float* x      = (const float*)d_in[0];   // [4096,512]
    const float* Hmat   = (const float*)d_in[1];   // [4096,4096]
    const float* proj_w = (const float*)d_in[2];   // [512,512]
    const float* proj_b = (const float*)d_in[3];   // [512]
    const float* w1     = (const float*)d_in[4];   // [4096,4096]
    const float* w2     = (const float*)d_in[5];   // [4096,4096]
    float* out = (float*)d_out;

    char* ws = (char*)d_ws;
    unsigned short* xnh   = (unsigned short*)(ws + 0);         // 4 MB
    unsigned short* xnl   = (unsigned short*)(ws + 4194304);   // 4 MB
    float*          cosm  = (float*)(ws + 8388608);            // 64 MB, dead after topk_fix
    int*            elist = (int*)  (ws + 8388608);            // 4 MB (aliases dead cos)
    float*          eval_ = (float*)(ws + 12582912);           // 4 MB (aliases dead cos)
    float*          h     = (float*)(ws + 25165824);           // 8 MB (aliases dead cos)
    float*          h2    = (float*)(ws + 33554432);           // 8 MB (aliases dead cos)
    unsigned short* whi   = (unsigned short*)(ws + 50331648);  // 512 KB (aliases dead cos)
    unsigned short* wlo   = (unsigned short*)(ws + 50855936);  // 512 KB (aliases dead cos)
    unsigned*       maskT = (unsigned*)(ws + 75497472);        // 2 MB
    int*            ecnt    = (int*)(ws + 77594624);           // 16 KB
    int*            rcnt    = (int*)(ws + 77611008);           // 16 KB
    float*          norminv = (float*)(ws + 77627392);         // 16 KB
    float*          nrm     = (float*)(ws + 77643776);         // 16 KB
    int*            rlist   = (int*)(ws + 77676544);           // 4 MB
    float*          rval    = (float*)(ws + 81870848);         // 4 MB
    int*            cnt16   = (int*)(ws + 86065152);           // 256 KB

    // 1. norms + bf16 hi/lo of xn
    rownorm_k<<<N, 256, 0, stream>>>(x, xnh, xnl, norminv, nrm);
    // 2. approx cos: upper-tri MFMA + fused mirror, swizzled LDS, XCD blocks
    cos_gemm_k<<<CNB * (CNB + 1) / 2, 256, 0, stream>>>(xnh, xnl, cosm);
    // 3. fused top-k (prefiltered) + threshold + inline exact fix
    topk_fix_k<<<N, 256, 0, stream>>>(cosm, x, norminv, maskT, w2, Hmat,
                                      rlist, rval, rcnt);
    // 4. h = nrm*(xn @ proj_w^T) + b (cos region now dead; h aliases it)
    cast_w_k<<<256, 256, 0, stream>>>(proj_w, whi, wlo);
    proj_mfma_k<<<dim3(OUT_FT / 64, N / 64), 256, 0, stream>>>(xnh, xnl, whi, wlo,
                                                               proj_b, nrm, h);
    // 5. column lists: count -> fill at prefix offsets
    count_cols_k<<<dim3(16, 16), 256, 0, stream>>>(maskT, cnt16);
    fill_cols_k<<<dim3(16, 16), 256, 0, stream>>>(maskT, cnt16, w1, Hmat, elist, eval_, ecnt);
    // 6. h2[e,:] = normalize . gather-sum over column lists
    spmm_k<<<N, 256, 0, stream>>>(elist, eval_, ecnt, h, h2);
    // 7. out[v,:] = normalize . gather-sum over row lists
    spmm_k<<<N, 256, 0, stream>>>(rlist, rval, rcnt, h2, out);
}